// Round 18
// baseline (159.815 us; speedup 1.0000x reference)
//
#include <hip/hip_runtime.h>
#include <stdint.h>

#define BATCH 32
#define CH    256
#define TLEN  4096
#define TN    128           // timesteps per block tile
#define NROW  132           // sA rows: 2 halo + 128 + 2 halo
#define TPAD  4100          // aT rows per batch strip: 2 pad + 4096 + 2 pad
#define SST   68            // phase-B f32 scratch row stride

typedef short    bf16x8 __attribute__((ext_vector_type(8)));
typedef float    f32x4  __attribute__((ext_vector_type(4)));
typedef uint16_t u16x4  __attribute__((ext_vector_type(4)));
typedef uint16_t u16x8  __attribute__((ext_vector_type(8)));

// packed fragment-order weights: g_wpk[(s*CH + co)*32 + g*8 + e] = w1eff[co][32s+8g+e]
__device__ __attribute__((aligned(16))) uint16_t g_wpk[CH * CH];
__device__ __attribute__((aligned(16))) float g_tap[5 * CH];   // tap-major
__device__ __attribute__((aligned(16))) float g_bias[CH];

static __device__ __forceinline__ uint16_t f32_to_bf16(float f) {
    uint32_t u = __builtin_bit_cast(uint32_t, f);
    u += 0x7FFFu + ((u >> 16) & 1u);
    return (uint16_t)(u >> 16);
}
static __device__ __forceinline__ float bf16_to_f32(uint16_t h) {
    uint32_t u = ((uint32_t)h) << 16;
    return __builtin_bit_cast(float, u);
}
// tanh-form gelu folded into exp2
static __device__ __forceinline__ float gelu_fast(float x) {
    const float A = 2.3022082f;
    const float B = 0.10294331f;
    float x2 = x * x;
    float z  = x * fmaf(x2, B, A);
    float e  = exp2f(z);
    float r  = __builtin_amdgcn_rcpf(1.0f + e);
    return fmaf(-x, r, x);
}

__global__ void prep_kernel(const float* __restrict__ w1, const float* __restrict__ b1,
                            const float* __restrict__ w3, const float* __restrict__ b3,
                            const float* __restrict__ w5, const float* __restrict__ b5,
                            const float* __restrict__ wc, const float* __restrict__ bc) {
    const int o = blockIdx.x;
    const int c = threadIdx.x;
    const float wc0 = wc[o * 3 + 0];
    const int s = c >> 5, g = (c >> 3) & 3, e = c & 7;
    g_wpk[(s * CH + o) * 32 + g * 8 + e] = f32_to_bf16(wc0 * w1[o * CH + c]);
    if (c == 0) {
        const float wc1 = wc[o * 3 + 1], wc2 = wc[o * 3 + 2];
        g_tap[0 * CH + o] = wc2 * w5[o * 5 + 0];
        g_tap[1 * CH + o] = wc1 * w3[o * 3 + 0] + wc2 * w5[o * 5 + 1];
        g_tap[2 * CH + o] = wc1 * w3[o * 3 + 1] + wc2 * w5[o * 5 + 2];
        g_tap[3 * CH + o] = wc1 * w3[o * 3 + 2] + wc2 * w5[o * 5 + 3];
        g_tap[4 * CH + o] = wc2 * w5[o * 5 + 4];
        g_bias[o] = wc0 * b1[o] + wc1 * b3[o] + wc2 * b5[o] + bc[o];
    }
}

// k1: gelu + cast + transpose into aT[b][strip_row][c] bf16, where
// strip_row = 2 + t, element (t,c) stored at col c ^ ((t&7)<<3).
// sL swizzle: element (c=cr, t) lives at sL[cr*72 + ((t&7) | (((t>>3)^(cr>>3))<<3))]
__global__ __launch_bounds__(256, 4)
void gelu_tr_kernel(const float* __restrict__ x, uint16_t* __restrict__ aT) {
    __shared__ __attribute__((aligned(16))) uint16_t sL[64 * 72];   // 9216 B

    const int tid = threadIdx.x;
    const int tb = blockIdx.x, cb = blockIdx.y, b = blockIdx.z;
    const int t0 = tb * 64, c0 = cb * 64;

    {
        const int cr = tid >> 2;       // 0..63 channel-local
        const int q  = tid & 3;        // 0..3 t-quarter (16 t)
        const float* xr = x + ((size_t)(b * CH + c0 + cr)) * TLEN + t0 + q * 16;
        f32x4 v0 = *(const f32x4*)(xr + 0);
        f32x4 v1 = *(const f32x4*)(xr + 4);
        f32x4 v2 = *(const f32x4*)(xr + 8);
        f32x4 v3 = *(const f32x4*)(xr + 12);
        u16x8 p0, p1;
#pragma unroll
        for (int j = 0; j < 4; ++j) {
            p0[j]     = f32_to_bf16(gelu_fast(v0[j]));
            p0[4 + j] = f32_to_bf16(gelu_fast(v1[j]));
            p1[j]     = f32_to_bf16(gelu_fast(v2[j]));
            p1[4 + j] = f32_to_bf16(gelu_fast(v3[j]));
        }
        const int b0 = (((q * 2 + 0) ^ (cr >> 3)) << 3);
        const int b1 = (((q * 2 + 1) ^ (cr >> 3)) << 3);
        *(u16x8*)(&sL[cr * 72 + b0]) = p0;
        *(u16x8*)(&sL[cr * 72 + b1]) = p1;
    }
    __syncthreads();

    uint16_t* aTb = aT + (size_t)b * TPAD * CH;
#pragma unroll
    for (int i = 0; i < 2; ++i) {
        const int idx = tid + i * 256;
        const int tr  = idx >> 3;      // 0..63
        const int ch  = idx & 7;       // 0..7 c-chunk
        const int t   = t0 + tr;
        const int swz = (t & 7) << 3;
        const int cin = (tr & 7) | ((((tr >> 3) ^ ch) & 7) << 3);
        u16x8 o;
#pragma unroll
        for (int j = 0; j < 8; ++j) o[j] = sL[(ch * 8 + j) * 72 + cin];
        *(u16x8*)(&aTb[(size_t)(2 + t) * CH + ((c0 + ch * 8) ^ swz)]) = o;
    }
    if (tb == 0) {
        const int pr = tid >> 6;       // 0..3
        const int cc = c0 + (tid & 63);
        const int prow = (pr < 2) ? pr : (4098 + (pr - 2));
        const int tmod = (pr < 2) ? (6 + pr) : (pr - 2);   // (t&7) of the pad row
        aTb[(size_t)prow * CH + (cc ^ (tmod << 3))] = 0;
    }
}

// k2: 512 threads = 8 waves (4 M-groups x 2 t-halves) per (b, 128-t tile).
// Linear 67.6 KB staging (loads issued before LDS writes), pipelined K-loop with
// packed coalesced weights (wave-pairs share panels), in-register depthwise fold,
// then sA storage reused as wave-private transpose scratch (barrier-protected).
// sA row r <-> global t = t0 + r - 2; swizzle of row r = ((r+6)&7)<<3.
__global__ __launch_bounds__(512, 4)
void gemm_kernel(const uint16_t* __restrict__ aT, const float* __restrict__ x,
                 float* __restrict__ out) {
    __shared__ __attribute__((aligned(16))) uint16_t sA[NROW * CH];   // 67584 B

    const int tid  = threadIdx.x;
    const int lane = tid & 63;
    const int wid  = tid >> 6;         // 0..7
    const int wm   = wid & 3;          // M-group (64 channels)
    const int wn   = wid >> 2;         // t-half (64 timesteps)
    const int b    = blockIdx.y;
    const int t0   = blockIdx.x * TN;

    const float* __restrict__ xb = x + (size_t)b * CH * TLEN;
    float* __restrict__ ob = out + (size_t)b * CH * TLEN;

    // ---- staging: 4224 16B chunks; all loads issued before any LDS write ----
    {
        const u16x8* gsrc = (const u16x8*)(aT + (size_t)b * TPAD * CH + (size_t)t0 * CH);
        u16x8 stg[8], stgT;
#pragma unroll
        for (int i = 0; i < 8; ++i) stg[i] = gsrc[tid + i * 512];
        const bool tail = (tid < 128);
        if (tail) stgT = gsrc[tid + 4096];
        u16x8* ldst = (u16x8*)sA;
#pragma unroll
        for (int i = 0; i < 8; ++i) ldst[tid + i * 512] = stg[i];
        if (tail) ldst[tid + 4096] = stgT;
    }
    __syncthreads();   // B1

    f32x4 acc[4][4];
    const f32x4 vzero = {0.f, 0.f, 0.f, 0.f};
#pragma unroll
    for (int mi = 0; mi < 4; ++mi)
#pragma unroll
        for (int ni = 0; ni < 4; ++ni) acc[mi][ni] = vzero;

    const int m0   = wm * 64;
    const int tn0  = wn * 64;
    const int colt = lane & 15;
    const int kgrp = (lane >> 4) * 8;

    // ---- K loop, 1-deep ping-pong; packed weights (contiguous 1KB/wave-load) ----
    const int swzB = (colt & 7) << 3;
    int rowB[4];
#pragma unroll
    for (int ni = 0; ni < 4; ++ni) rowB[ni] = (tn0 + ni * 16 + colt + 2) * CH;

    bf16x8 afb[2][4], bfb[2][4];
#pragma unroll
    for (int mi = 0; mi < 4; ++mi) {
        const int co = m0 + mi * 16 + colt;
        afb[0][mi] = *(const bf16x8*)(g_wpk + co * 32 + kgrp);
    }
#pragma unroll
    for (int ni = 0; ni < 4; ++ni)
        bfb[0][ni] = *(const bf16x8*)(&sA[rowB[ni] + (kgrp ^ swzB)]);
#pragma unroll
    for (int s = 0; s < 8; ++s) {
        const int cur = s & 1, nxt = cur ^ 1;
        if (s < 7) {
            const int sbase = (s + 1) * CH * 32;
#pragma unroll
            for (int mi = 0; mi < 4; ++mi) {
                const int co = m0 + mi * 16 + colt;
                afb[nxt][mi] = *(const bf16x8*)(g_wpk + sbase + co * 32 + kgrp);
            }
            const int cin = (s + 1) * 32 + kgrp;
#pragma unroll
            for (int ni = 0; ni < 4; ++ni)
                bfb[nxt][ni] = *(const bf16x8*)(&sA[rowB[ni] + (cin ^ swzB)]);
        }
#pragma unroll
        for (int mi = 0; mi < 4; ++mi)
#pragma unroll
            for (int ni = 0; ni < 4; ++ni)
                acc[mi][ni] = __builtin_amdgcn_mfma_f32_16x16x32_bf16(afb[cur][mi], bfb[cur][ni], acc[mi][ni], 0, 0, 0);
    }

    // ---- phase A: depthwise + bias folded into acc ----
    const int rg = (lane >> 4) * 4;
    int swzA[5];
#pragma unroll
    for (int k = 0; k < 5; ++k) swzA[k] = ((colt + k + 6) & 7) << 3;
#pragma unroll
    for (int mi = 0; mi < 4; ++mi) {
        const int c = m0 + mi * 16 + rg;
        const f32x4 tp0 = *(const f32x4*)(g_tap + 0 * CH + c);
        const f32x4 tp1 = *(const f32x4*)(g_tap + 1 * CH + c);
        const f32x4 tp2 = *(const f32x4*)(g_tap + 2 * CH + c);
        const f32x4 tp3 = *(const f32x4*)(g_tap + 3 * CH + c);
        const f32x4 tp4 = *(const f32x4*)(g_tap + 4 * CH + c);
        const f32x4 bsv = *(const f32x4*)(g_bias + c);
#pragma unroll
        for (int ni = 0; ni < 4; ++ni) {
            const int t = tn0 + ni * 16 + colt;     // sA row base (t .. t+4)
            u16x4 a0 = *(const u16x4*)(&sA[(t + 0) * CH + (c ^ swzA[0])]);
            u16x4 a1 = *(const u16x4*)(&sA[(t + 1) * CH + (c ^ swzA[1])]);
            u16x4 a2 = *(const u16x4*)(&sA[(t + 2) * CH + (c ^ swzA[2])]);
            u16x4 a3 = *(const u16x4*)(&sA[(t + 3) * CH + (c ^ swzA[3])]);
            u16x4 a4 = *(const u16x4*)(&sA[(t + 4) * CH + (c ^ swzA[4])]);
#pragma unroll
            for (int r = 0; r < 4; ++r) {
                float d = tp0[r] * bf16_to_f32(a0[r]);
                d = fmaf(tp1[r], bf16_to_f32(a1[r]), d);
                d = fmaf(tp2[r], bf16_to_f32(a2[r]), d);
                d = fmaf(tp3[r], bf16_to_f32(a3[r]), d);
                d = fmaf(tp4[r], bf16_to_f32(a4[r]), d);
                acc[mi][ni][r] += d + bsv[r];
            }
        }
    }
    __syncthreads();   // B2: all sA reads done; sA storage becomes f32 scratch

    // ---- phase B: wave-private transpose through sA; exact f32 residual ----
    float* __restrict__ sw = ((float*)sA) + wid * (16 * SST);   // 4352 B per wave
    const int ci = lane >> 2;          // 0..15 channel-local
    const int q  = lane & 3;           // 0..3 -> 16 t each

#pragma unroll
    for (int mi = 0; mi < 4; ++mi) {
        const int cc = m0 + mi * 16 + ci;
        const float* xrow = xb + (size_t)cc * TLEN + t0 + tn0 + q * 16;
        f32x4 xv0 = *(const f32x4*)(xrow + 0);
        f32x4 xv1 = *(const f32x4*)(xrow + 4);
        f32x4 xv2 = *(const f32x4*)(xrow + 8);
        f32x4 xv3 = *(const f32x4*)(xrow + 12);
#pragma unroll
        for (int ni = 0; ni < 4; ++ni) {
            const int t = ni * 16 + colt;
#pragma unroll
            for (int r = 0; r < 4; ++r) sw[(rg + r) * SST + t] = acc[mi][ni][r];
        }
        float* orow = ob + (size_t)cc * TLEN + t0 + tn0 + q * 16;
        const float* srow = sw + ci * SST + q * 16;
        f32x4 s0 = *(const f32x4*)(srow + 0);
        f32x4 s1 = *(const f32x4*)(srow + 4);
        f32x4 s2 = *(const f32x4*)(srow + 8);
        f32x4 s3 = *(const f32x4*)(srow + 12);
        *(f32x4*)(orow + 0)  = s0 + xv0;
        *(f32x4*)(orow + 4)  = s1 + xv1;
        *(f32x4*)(orow + 8)  = s2 + xv2;
        *(f32x4*)(orow + 12) = s3 + xv3;
    }
}

extern "C" void kernel_launch(void* const* d_in, const int* in_sizes, int n_in,
                              void* d_out, int out_size, void* d_ws, size_t ws_size,
                              hipStream_t stream) {
    const float* x  = (const float*)d_in[0];
    const float* w1 = (const float*)d_in[1];
    const float* b1 = (const float*)d_in[2];
    const float* w3 = (const float*)d_in[3];
    const float* b3 = (const float*)d_in[4];
    const float* w5 = (const float*)d_in[5];
    const float* b5 = (const float*)d_in[6];
    const float* wc = (const float*)d_in[7];
    const float* bc = (const float*)d_in[8];
    float* out = (float*)d_out;
    uint16_t* aT = (uint16_t*)d_ws;    // 32*4100*256*2 B = 67.2 MB

    prep_kernel<<<dim3(CH), dim3(CH), 0, stream>>>(w1, b1, w3, b3, w5, b5, wc, bc);
    gelu_tr_kernel<<<dim3(TLEN / 64, CH / 64, BATCH), dim3(256), 0, stream>>>(x, aT);
    gemm_kernel<<<dim3(TLEN / TN, BATCH), dim3(512), 0, stream>>>(aT, x, out);
}

// Round 19
// 136.132 us; speedup vs baseline: 1.1740x; 1.1740x over previous
//
#include <hip/hip_runtime.h>
#include <stdint.h>

#define BATCH 32
#define CH    256
#define TLEN  4096
#define TN    128           // timesteps per block tile
#define NROW  132           // sA rows: 2 halo + 128 + 2 halo
#define TPAD  4100          // aT rows per batch strip: 2 pad + 4096 + 2 pad
#define SST   68            // phase-B f32 scratch row stride

typedef short    bf16x8 __attribute__((ext_vector_type(8)));
typedef float    f32x4  __attribute__((ext_vector_type(4)));
typedef uint16_t u16x4  __attribute__((ext_vector_type(4)));
typedef uint16_t u16x8  __attribute__((ext_vector_type(8)));

// packed fragment-order weights: g_wpk[(s*CH + co)*32 + g*8 + e] = w1eff[co][32s+8g+e]
__device__ __attribute__((aligned(16))) uint16_t g_wpk[CH * CH];
__device__ __attribute__((aligned(16))) float g_tap[5 * CH];   // tap-major
__device__ __attribute__((aligned(16))) float g_bias[CH];

static __device__ __forceinline__ uint16_t f32_to_bf16(float f) {
    uint32_t u = __builtin_bit_cast(uint32_t, f);
    u += 0x7FFFu + ((u >> 16) & 1u);
    return (uint16_t)(u >> 16);
}
static __device__ __forceinline__ float bf16_to_f32(uint16_t h) {
    uint32_t u = ((uint32_t)h) << 16;
    return __builtin_bit_cast(float, u);
}
// tanh-form gelu folded into exp2
static __device__ __forceinline__ float gelu_fast(float x) {
    const float A = 2.3022082f;
    const float B = 0.10294331f;
    float x2 = x * x;
    float z  = x * fmaf(x2, B, A);
    float e  = exp2f(z);
    float r  = __builtin_amdgcn_rcpf(1.0f + e);
    return fmaf(-x, r, x);
}

__global__ void prep_kernel(const float* __restrict__ w1, const float* __restrict__ b1,
                            const float* __restrict__ w3, const float* __restrict__ b3,
                            const float* __restrict__ w5, const float* __restrict__ b5,
                            const float* __restrict__ wc, const float* __restrict__ bc) {
    const int o = blockIdx.x;
    const int c = threadIdx.x;
    const float wc0 = wc[o * 3 + 0];
    const int s = c >> 5, g = (c >> 3) & 3, e = c & 7;
    g_wpk[(s * CH + o) * 32 + g * 8 + e] = f32_to_bf16(wc0 * w1[o * CH + c]);
    if (c == 0) {
        const float wc1 = wc[o * 3 + 1], wc2 = wc[o * 3 + 2];
        g_tap[0 * CH + o] = wc2 * w5[o * 5 + 0];
        g_tap[1 * CH + o] = wc1 * w3[o * 3 + 0] + wc2 * w5[o * 5 + 1];
        g_tap[2 * CH + o] = wc1 * w3[o * 3 + 1] + wc2 * w5[o * 5 + 2];
        g_tap[3 * CH + o] = wc1 * w3[o * 3 + 2] + wc2 * w5[o * 5 + 3];
        g_tap[4 * CH + o] = wc2 * w5[o * 5 + 4];
        g_bias[o] = wc0 * b1[o] + wc1 * b3[o] + wc2 * b5[o] + bc[o];
    }
}

// k1: gelu + cast + transpose into aT[b][strip_row][c] bf16, where
// strip_row = 2 + t, element (t,c) stored at col c ^ ((t&7)<<3).
// sL swizzle: element (c=cr, t) lives at sL[cr*72 + ((t&7) | (((t>>3)^(cr>>3))<<3))]
__global__ __launch_bounds__(256, 4)
void gelu_tr_kernel(const float* __restrict__ x, uint16_t* __restrict__ aT) {
    __shared__ __attribute__((aligned(16))) uint16_t sL[64 * 72];   // 9216 B

    const int tid = threadIdx.x;
    const int tb = blockIdx.x, cb = blockIdx.y, b = blockIdx.z;
    const int t0 = tb * 64, c0 = cb * 64;

    {
        const int cr = tid >> 2;       // 0..63 channel-local
        const int q  = tid & 3;        // 0..3 t-quarter (16 t)
        const float* xr = x + ((size_t)(b * CH + c0 + cr)) * TLEN + t0 + q * 16;
        f32x4 v0 = *(const f32x4*)(xr + 0);
        f32x4 v1 = *(const f32x4*)(xr + 4);
        f32x4 v2 = *(const f32x4*)(xr + 8);
        f32x4 v3 = *(const f32x4*)(xr + 12);
        u16x8 p0, p1;
#pragma unroll
        for (int j = 0; j < 4; ++j) {
            p0[j]     = f32_to_bf16(gelu_fast(v0[j]));
            p0[4 + j] = f32_to_bf16(gelu_fast(v1[j]));
            p1[j]     = f32_to_bf16(gelu_fast(v2[j]));
            p1[4 + j] = f32_to_bf16(gelu_fast(v3[j]));
        }
        const int b0 = (((q * 2 + 0) ^ (cr >> 3)) << 3);
        const int b1 = (((q * 2 + 1) ^ (cr >> 3)) << 3);
        *(u16x8*)(&sL[cr * 72 + b0]) = p0;
        *(u16x8*)(&sL[cr * 72 + b1]) = p1;
    }
    __syncthreads();

    uint16_t* aTb = aT + (size_t)b * TPAD * CH;
#pragma unroll
    for (int i = 0; i < 2; ++i) {
        const int idx = tid + i * 256;
        const int tr  = idx >> 3;      // 0..63
        const int ch  = idx & 7;       // 0..7 c-chunk
        const int t   = t0 + tr;
        const int swz = (t & 7) << 3;
        const int cin = (tr & 7) | ((((tr >> 3) ^ ch) & 7) << 3);
        u16x8 o;
#pragma unroll
        for (int j = 0; j < 8; ++j) o[j] = sL[(ch * 8 + j) * 72 + cin];
        *(u16x8*)(&aTb[(size_t)(2 + t) * CH + ((c0 + ch * 8) ^ swz)]) = o;
    }
    if (tb == 0) {
        const int pr = tid >> 6;       // 0..3
        const int cc = c0 + (tid & 63);
        const int prow = (pr < 2) ? pr : (4098 + (pr - 2));
        const int tmod = (pr < 2) ? (6 + pr) : (pr - 2);   // (t&7) of the pad row
        aTb[(size_t)prow * CH + (cc ^ (tmod << 3))] = 0;
    }
}

// k2: 512 threads = 8 waves (4 M-groups x 2 t-halves) per (b, 128-t tile).
// Linear 67.6 KB staging (loads issued before LDS writes), pipelined K-loop with
// packed coalesced weights (wave-pairs share panels), in-register depthwise fold,
// then sA storage reused as wave-private transpose scratch (barrier-protected).
// sA row r <-> global t = t0 + r - 2; swizzle of row r = ((r+6)&7)<<3.
// launch_bounds(512,2): VGPR cap ~256/2=128 (empirical rule) -> no spill.
__global__ __launch_bounds__(512, 2)
void gemm_kernel(const uint16_t* __restrict__ aT, const float* __restrict__ x,
                 float* __restrict__ out) {
    __shared__ __attribute__((aligned(16))) uint16_t sA[NROW * CH];   // 67584 B

    const int tid  = threadIdx.x;
    const int lane = tid & 63;
    const int wid  = tid >> 6;         // 0..7
    const int wm   = wid & 3;          // M-group (64 channels)
    const int wn   = wid >> 2;         // t-half (64 timesteps)
    const int b    = blockIdx.y;
    const int t0   = blockIdx.x * TN;

    const float* __restrict__ xb = x + (size_t)b * CH * TLEN;
    float* __restrict__ ob = out + (size_t)b * CH * TLEN;

    // ---- staging: 4224 16B chunks; all loads issued before any LDS write ----
    {
        const u16x8* gsrc = (const u16x8*)(aT + (size_t)b * TPAD * CH + (size_t)t0 * CH);
        u16x8 stg[8], stgT;
#pragma unroll
        for (int i = 0; i < 8; ++i) stg[i] = gsrc[tid + i * 512];
        const bool tail = (tid < 128);
        if (tail) stgT = gsrc[tid + 4096];
        u16x8* ldst = (u16x8*)sA;
#pragma unroll
        for (int i = 0; i < 8; ++i) ldst[tid + i * 512] = stg[i];
        if (tail) ldst[tid + 4096] = stgT;
    }
    __syncthreads();   // B1

    f32x4 acc[4][4];
    const f32x4 vzero = {0.f, 0.f, 0.f, 0.f};
#pragma unroll
    for (int mi = 0; mi < 4; ++mi)
#pragma unroll
        for (int ni = 0; ni < 4; ++ni) acc[mi][ni] = vzero;

    const int m0   = wm * 64;
    const int tn0  = wn * 64;
    const int colt = lane & 15;
    const int kgrp = (lane >> 4) * 8;

    // ---- K loop, 1-deep ping-pong; packed weights (contiguous 1KB/wave-load) ----
    const int swzB = (colt & 7) << 3;
    int rowB[4];
#pragma unroll
    for (int ni = 0; ni < 4; ++ni) rowB[ni] = (tn0 + ni * 16 + colt + 2) * CH;

    bf16x8 afb[2][4], bfb[2][4];
#pragma unroll
    for (int mi = 0; mi < 4; ++mi) {
        const int co = m0 + mi * 16 + colt;
        afb[0][mi] = *(const bf16x8*)(g_wpk + co * 32 + kgrp);
    }
#pragma unroll
    for (int ni = 0; ni < 4; ++ni)
        bfb[0][ni] = *(const bf16x8*)(&sA[rowB[ni] + (kgrp ^ swzB)]);
#pragma unroll
    for (int s = 0; s < 8; ++s) {
        const int cur = s & 1, nxt = cur ^ 1;
        if (s < 7) {
            const int sbase = (s + 1) * CH * 32;
#pragma unroll
            for (int mi = 0; mi < 4; ++mi) {
                const int co = m0 + mi * 16 + colt;
                afb[nxt][mi] = *(const bf16x8*)(g_wpk + sbase + co * 32 + kgrp);
            }
            const int cin = (s + 1) * 32 + kgrp;
#pragma unroll
            for (int ni = 0; ni < 4; ++ni)
                bfb[nxt][ni] = *(const bf16x8*)(&sA[rowB[ni] + (cin ^ swzB)]);
        }
#pragma unroll
        for (int mi = 0; mi < 4; ++mi)
#pragma unroll
            for (int ni = 0; ni < 4; ++ni)
                acc[mi][ni] = __builtin_amdgcn_mfma_f32_16x16x32_bf16(afb[cur][mi], bfb[cur][ni], acc[mi][ni], 0, 0, 0);
    }

    // ---- phase A: depthwise + bias folded into acc ----
    const int rg = (lane >> 4) * 4;
    int swzA[5];
#pragma unroll
    for (int k = 0; k < 5; ++k) swzA[k] = ((colt + k + 6) & 7) << 3;
#pragma unroll
    for (int mi = 0; mi < 4; ++mi) {
        const int c = m0 + mi * 16 + rg;
        const f32x4 tp0 = *(const f32x4*)(g_tap + 0 * CH + c);
        const f32x4 tp1 = *(const f32x4*)(g_tap + 1 * CH + c);
        const f32x4 tp2 = *(const f32x4*)(g_tap + 2 * CH + c);
        const f32x4 tp3 = *(const f32x4*)(g_tap + 3 * CH + c);
        const f32x4 tp4 = *(const f32x4*)(g_tap + 4 * CH + c);
        const f32x4 bsv = *(const f32x4*)(g_bias + c);
#pragma unroll
        for (int ni = 0; ni < 4; ++ni) {
            const int t = tn0 + ni * 16 + colt;     // sA row base (t .. t+4)
            u16x4 a0 = *(const u16x4*)(&sA[(t + 0) * CH + (c ^ swzA[0])]);
            u16x4 a1 = *(const u16x4*)(&sA[(t + 1) * CH + (c ^ swzA[1])]);
            u16x4 a2 = *(const u16x4*)(&sA[(t + 2) * CH + (c ^ swzA[2])]);
            u16x4 a3 = *(const u16x4*)(&sA[(t + 3) * CH + (c ^ swzA[3])]);
            u16x4 a4 = *(const u16x4*)(&sA[(t + 4) * CH + (c ^ swzA[4])]);
#pragma unroll
            for (int r = 0; r < 4; ++r) {
                float d = tp0[r] * bf16_to_f32(a0[r]);
                d = fmaf(tp1[r], bf16_to_f32(a1[r]), d);
                d = fmaf(tp2[r], bf16_to_f32(a2[r]), d);
                d = fmaf(tp3[r], bf16_to_f32(a3[r]), d);
                d = fmaf(tp4[r], bf16_to_f32(a4[r]), d);
                acc[mi][ni][r] += d + bsv[r];
            }
        }
    }
    __syncthreads();   // B2: all sA reads done; sA storage becomes f32 scratch

    // ---- phase B: wave-private transpose through sA; exact f32 residual ----
    float* __restrict__ sw = ((float*)sA) + wid * (16 * SST);   // 4352 B per wave
    const int ci = lane >> 2;          // 0..15 channel-local
    const int q  = lane & 3;           // 0..3 -> 16 t each

#pragma unroll
    for (int mi = 0; mi < 4; ++mi) {
        const int cc = m0 + mi * 16 + ci;
        const float* xrow = xb + (size_t)cc * TLEN + t0 + tn0 + q * 16;
        f32x4 xv0 = *(const f32x4*)(xrow + 0);
        f32x4 xv1 = *(const f32x4*)(xrow + 4);
        f32x4 xv2 = *(const f32x4*)(xrow + 8);
        f32x4 xv3 = *(const f32x4*)(xrow + 12);
#pragma unroll
        for (int ni = 0; ni < 4; ++ni) {
            const int t = ni * 16 + colt;
#pragma unroll
            for (int r = 0; r < 4; ++r) sw[(rg + r) * SST + t] = acc[mi][ni][r];
        }
        float* orow = ob + (size_t)cc * TLEN + t0 + tn0 + q * 16;
        const float* srow = sw + ci * SST + q * 16;
        f32x4 s0 = *(const f32x4*)(srow + 0);
        f32x4 s1 = *(const f32x4*)(srow + 4);
        f32x4 s2 = *(const f32x4*)(srow + 8);
        f32x4 s3 = *(const f32x4*)(srow + 12);
        *(f32x4*)(orow + 0)  = s0 + xv0;
        *(f32x4*)(orow + 4)  = s1 + xv1;
        *(f32x4*)(orow + 8)  = s2 + xv2;
        *(f32x4*)(orow + 12) = s3 + xv3;
    }
}

extern "C" void kernel_launch(void* const* d_in, const int* in_sizes, int n_in,
                              void* d_out, int out_size, void* d_ws, size_t ws_size,
                              hipStream_t stream) {
    const float* x  = (const float*)d_in[0];
    const float* w1 = (const float*)d_in[1];
    const float* b1 = (const float*)d_in[2];
    const float* w3 = (const float*)d_in[3];
    const float* b3 = (const float*)d_in[4];
    const float* w5 = (const float*)d_in[5];
    const float* b5 = (const float*)d_in[6];
    const float* wc = (const float*)d_in[7];
    const float* bc = (const float*)d_in[8];
    float* out = (float*)d_out;
    uint16_t* aT = (uint16_t*)d_ws;    // 32*4100*256*2 B = 67.2 MB

    prep_kernel<<<dim3(CH), dim3(CH), 0, stream>>>(w1, b1, w3, b3, w5, b5, wc, bc);
    gelu_tr_kernel<<<dim3(TLEN / 64, CH / 64, BATCH), dim3(256), 0, stream>>>(x, aT);
    gemm_kernel<<<dim3(TLEN / TN, BATCH), dim3(512), 0, stream>>>(aT, x, out);
}

// Round 20
// 124.910 us; speedup vs baseline: 1.2794x; 1.0898x over previous
//
#include <hip/hip_runtime.h>
#include <stdint.h>

#define BATCH 32
#define CH    256
#define TLEN  4096
#define TN    64
#define TPAD  4100          // aT rows per batch strip: 2 pad + 4096 + 2 pad
#define SST   68            // phase-B f32 scratch row stride

typedef short    bf16x8 __attribute__((ext_vector_type(8)));
typedef float    f32x4  __attribute__((ext_vector_type(4)));
typedef uint16_t u16x4  __attribute__((ext_vector_type(4)));
typedef uint16_t u16x8  __attribute__((ext_vector_type(8)));

// packed fragment-order weights: g_wpk[(s*CH + co)*32 + g*8 + e] = w1eff[co][32s+8g+e]
__device__ __attribute__((aligned(16))) uint16_t g_wpk[CH * CH];
__device__ __attribute__((aligned(16))) float g_tap[5 * CH];   // tap-major
__device__ __attribute__((aligned(16))) float g_bias[CH];

static __device__ __forceinline__ uint16_t f32_to_bf16(float f) {
    uint32_t u = __builtin_bit_cast(uint32_t, f);
    u += 0x7FFFu + ((u >> 16) & 1u);
    return (uint16_t)(u >> 16);
}
static __device__ __forceinline__ float bf16_to_f32(uint16_t h) {
    uint32_t u = ((uint32_t)h) << 16;
    return __builtin_bit_cast(float, u);
}
// tanh-form gelu folded into exp2
static __device__ __forceinline__ float gelu_fast(float x) {
    const float A = 2.3022082f;
    const float B = 0.10294331f;
    float x2 = x * x;
    float z  = x * fmaf(x2, B, A);
    float e  = exp2f(z);
    float r  = __builtin_amdgcn_rcpf(1.0f + e);
    return fmaf(-x, r, x);
}

__global__ void prep_kernel(const float* __restrict__ w1, const float* __restrict__ b1,
                            const float* __restrict__ w3, const float* __restrict__ b3,
                            const float* __restrict__ w5, const float* __restrict__ b5,
                            const float* __restrict__ wc, const float* __restrict__ bc) {
    const int o = blockIdx.x;
    const int c = threadIdx.x;
    const float wc0 = wc[o * 3 + 0];
    const int s = c >> 5, g = (c >> 3) & 3, e = c & 7;
    g_wpk[(s * CH + o) * 32 + g * 8 + e] = f32_to_bf16(wc0 * w1[o * CH + c]);
    if (c == 0) {
        const float wc1 = wc[o * 3 + 1], wc2 = wc[o * 3 + 2];
        g_tap[0 * CH + o] = wc2 * w5[o * 5 + 0];
        g_tap[1 * CH + o] = wc1 * w3[o * 3 + 0] + wc2 * w5[o * 5 + 1];
        g_tap[2 * CH + o] = wc1 * w3[o * 3 + 1] + wc2 * w5[o * 5 + 2];
        g_tap[3 * CH + o] = wc1 * w3[o * 3 + 2] + wc2 * w5[o * 5 + 3];
        g_tap[4 * CH + o] = wc2 * w5[o * 5 + 4];
        g_bias[o] = wc0 * b1[o] + wc1 * b3[o] + wc2 * b5[o] + bc[o];
    }
}

// k1: gelu + cast + transpose into aT[b][strip_row][c] bf16, where
// strip_row = 2 + t, element (t,c) stored at col c ^ ((t&7)<<3).
// sL swizzle: element (c=cr, t) lives at sL[cr*72 + ((t&7) | (((t>>3)^(cr>>3))<<3))]
__global__ __launch_bounds__(256, 4)
void gelu_tr_kernel(const float* __restrict__ x, uint16_t* __restrict__ aT) {
    __shared__ __attribute__((aligned(16))) uint16_t sL[64 * 72];   // 9216 B

    const int tid = threadIdx.x;
    const int tb = blockIdx.x, cb = blockIdx.y, b = blockIdx.z;
    const int t0 = tb * 64, c0 = cb * 64;

    {
        const int cr = tid >> 2;       // 0..63 channel-local
        const int q  = tid & 3;        // 0..3 t-quarter (16 t)
        const float* xr = x + ((size_t)(b * CH + c0 + cr)) * TLEN + t0 + q * 16;
        f32x4 v0 = *(const f32x4*)(xr + 0);
        f32x4 v1 = *(const f32x4*)(xr + 4);
        f32x4 v2 = *(const f32x4*)(xr + 8);
        f32x4 v3 = *(const f32x4*)(xr + 12);
        u16x8 p0, p1;
#pragma unroll
        for (int j = 0; j < 4; ++j) {
            p0[j]     = f32_to_bf16(gelu_fast(v0[j]));
            p0[4 + j] = f32_to_bf16(gelu_fast(v1[j]));
            p1[j]     = f32_to_bf16(gelu_fast(v2[j]));
            p1[4 + j] = f32_to_bf16(gelu_fast(v3[j]));
        }
        const int b0 = (((q * 2 + 0) ^ (cr >> 3)) << 3);
        const int b1 = (((q * 2 + 1) ^ (cr >> 3)) << 3);
        *(u16x8*)(&sL[cr * 72 + b0]) = p0;
        *(u16x8*)(&sL[cr * 72 + b1]) = p1;
    }
    __syncthreads();

    uint16_t* aTb = aT + (size_t)b * TPAD * CH;
#pragma unroll
    for (int i = 0; i < 2; ++i) {
        const int idx = tid + i * 256;
        const int tr  = idx >> 3;      // 0..63
        const int ch  = idx & 7;       // 0..7 c-chunk
        const int t   = t0 + tr;
        const int swz = (t & 7) << 3;
        const int cin = (tr & 7) | ((((tr >> 3) ^ ch) & 7) << 3);
        u16x8 o;
#pragma unroll
        for (int j = 0; j < 8; ++j) o[j] = sL[(ch * 8 + j) * 72 + cin];
        *(u16x8*)(&aTb[(size_t)(2 + t) * CH + ((c0 + ch * 8) ^ swz)]) = o;
    }
    if (tb == 0) {
        const int pr = tid >> 6;       // 0..3
        const int cc = c0 + (tid & 63);
        const int prow = (pr < 2) ? pr : (4098 + (pr - 2));
        const int tmod = (pr < 2) ? (6 + pr) : (pr - 2);   // (t&7) of the pad row
        aTb[(size_t)prow * CH + (cc ^ (tmod << 3))] = 0;
    }
}

// k2 (r17 structure, sS deleted): per (b, 64-t tile): linear 34 KB staging
// (loads issued before LDS writes), pipelined K-loop with packed coalesced
// weights, in-register depthwise fold, then sA storage reused as wave-private
// transpose scratch (barrier-protected). LDS = 34.8 KB -> 4 blocks/CU.
// sA row r <-> global t = t0 + r - 2; swizzle of row r = ((r+6)&7)<<3.
__global__ __launch_bounds__(256, 3)
void gemm_kernel(const uint16_t* __restrict__ aT, const float* __restrict__ x,
                 float* __restrict__ out) {
    __shared__ __attribute__((aligned(16))) uint16_t sA[68 * CH];      // 34816 B

    const int tid  = threadIdx.x;
    const int lane = tid & 63;
    const int wid  = tid >> 6;
    const int b    = blockIdx.y;
    const int t0   = blockIdx.x * TN;

    const float* __restrict__ xb = x + (size_t)b * CH * TLEN;
    float* __restrict__ ob = out + (size_t)b * CH * TLEN;

    // ---- staging: 2176 16B chunks; all loads issued before any LDS write ----
    {
        const u16x8* gsrc = (const u16x8*)(aT + (size_t)b * TPAD * CH + (size_t)t0 * CH);
        u16x8 stg[8], stgT;
#pragma unroll
        for (int i = 0; i < 8; ++i) stg[i] = gsrc[tid + i * 256];
        const bool tail = (tid < 128);
        if (tail) stgT = gsrc[tid + 2048];
        u16x8* ldst = (u16x8*)sA;
#pragma unroll
        for (int i = 0; i < 8; ++i) ldst[tid + i * 256] = stg[i];
        if (tail) ldst[tid + 2048] = stgT;
    }
    __syncthreads();   // B1

    f32x4 acc[4][4];
    const f32x4 vzero = {0.f, 0.f, 0.f, 0.f};
#pragma unroll
    for (int mi = 0; mi < 4; ++mi)
#pragma unroll
        for (int ni = 0; ni < 4; ++ni) acc[mi][ni] = vzero;

    const int m0   = wid * 64;
    const int colt = lane & 15;
    const int kgrp = (lane >> 4) * 8;

    // ---- K loop, 1-deep ping-pong; packed weights (contiguous 1KB/wave-load) ----
    const int swzB = (colt & 7) << 3;
    int rowB[4];
#pragma unroll
    for (int ni = 0; ni < 4; ++ni) rowB[ni] = (ni * 16 + colt + 2) * CH;

    bf16x8 afb[2][4], bfb[2][4];
#pragma unroll
    for (int mi = 0; mi < 4; ++mi) {
        const int co = m0 + mi * 16 + colt;
        afb[0][mi] = *(const bf16x8*)(g_wpk + co * 32 + kgrp);
    }
#pragma unroll
    for (int ni = 0; ni < 4; ++ni)
        bfb[0][ni] = *(const bf16x8*)(&sA[rowB[ni] + (kgrp ^ swzB)]);
#pragma unroll
    for (int s = 0; s < 8; ++s) {
        const int cur = s & 1, nxt = cur ^ 1;
        if (s < 7) {
            const int sbase = (s + 1) * CH * 32;
#pragma unroll
            for (int mi = 0; mi < 4; ++mi) {
                const int co = m0 + mi * 16 + colt;
                afb[nxt][mi] = *(const bf16x8*)(g_wpk + sbase + co * 32 + kgrp);
            }
            const int cin = (s + 1) * 32 + kgrp;
#pragma unroll
            for (int ni = 0; ni < 4; ++ni)
                bfb[nxt][ni] = *(const bf16x8*)(&sA[rowB[ni] + (cin ^ swzB)]);
        }
#pragma unroll
        for (int mi = 0; mi < 4; ++mi)
#pragma unroll
            for (int ni = 0; ni < 4; ++ni)
                acc[mi][ni] = __builtin_amdgcn_mfma_f32_16x16x32_bf16(afb[cur][mi], bfb[cur][ni], acc[mi][ni], 0, 0, 0);
    }

    // ---- phase A: depthwise + bias folded into acc ----
    const int rg = (lane >> 4) * 4;
    int swzA[5];
#pragma unroll
    for (int k = 0; k < 5; ++k) swzA[k] = ((colt + k + 6) & 7) << 3;
#pragma unroll
    for (int mi = 0; mi < 4; ++mi) {
        const int c = m0 + mi * 16 + rg;
        const f32x4 tp0 = *(const f32x4*)(g_tap + 0 * CH + c);
        const f32x4 tp1 = *(const f32x4*)(g_tap + 1 * CH + c);
        const f32x4 tp2 = *(const f32x4*)(g_tap + 2 * CH + c);
        const f32x4 tp3 = *(const f32x4*)(g_tap + 3 * CH + c);
        const f32x4 tp4 = *(const f32x4*)(g_tap + 4 * CH + c);
        const f32x4 bsv = *(const f32x4*)(g_bias + c);
#pragma unroll
        for (int ni = 0; ni < 4; ++ni) {
            const int t = ni * 16 + colt;
            u16x4 a0 = *(const u16x4*)(&sA[(t + 0) * CH + (c ^ swzA[0])]);
            u16x4 a1 = *(const u16x4*)(&sA[(t + 1) * CH + (c ^ swzA[1])]);
            u16x4 a2 = *(const u16x4*)(&sA[(t + 2) * CH + (c ^ swzA[2])]);
            u16x4 a3 = *(const u16x4*)(&sA[(t + 3) * CH + (c ^ swzA[3])]);
            u16x4 a4 = *(const u16x4*)(&sA[(t + 4) * CH + (c ^ swzA[4])]);
#pragma unroll
            for (int r = 0; r < 4; ++r) {
                float d = tp0[r] * bf16_to_f32(a0[r]);
                d = fmaf(tp1[r], bf16_to_f32(a1[r]), d);
                d = fmaf(tp2[r], bf16_to_f32(a2[r]), d);
                d = fmaf(tp3[r], bf16_to_f32(a3[r]), d);
                d = fmaf(tp4[r], bf16_to_f32(a4[r]), d);
                acc[mi][ni][r] += d + bsv[r];
            }
        }
    }
    __syncthreads();   // B2: all sA reads done; sA storage becomes f32 scratch

    // ---- phase B: wave-private transpose through sA; exact f32 residual ----
    float* __restrict__ sw = ((float*)sA) + wid * (16 * SST);   // 4352 B per wave
    const int ci = lane >> 2;          // 0..15 channel-local
    const int q  = lane & 3;           // 0..3 -> 16 t each

#pragma unroll
    for (int mi = 0; mi < 4; ++mi) {
        const int cc = m0 + mi * 16 + ci;
        const float* xrow = xb + (size_t)cc * TLEN + t0 + q * 16;
        f32x4 xv0 = *(const f32x4*)(xrow + 0);
        f32x4 xv1 = *(const f32x4*)(xrow + 4);
        f32x4 xv2 = *(const f32x4*)(xrow + 8);
        f32x4 xv3 = *(const f32x4*)(xrow + 12);
#pragma unroll
        for (int ni = 0; ni < 4; ++ni) {
            const int t = ni * 16 + colt;
#pragma unroll
            for (int r = 0; r < 4; ++r) sw[(rg + r) * SST + t] = acc[mi][ni][r];
        }
        float* orow = ob + (size_t)cc * TLEN + t0 + q * 16;
        const float* srow = sw + ci * SST + q * 16;
        f32x4 s0 = *(const f32x4*)(srow + 0);
        f32x4 s1 = *(const f32x4*)(srow + 4);
        f32x4 s2 = *(const f32x4*)(srow + 8);
        f32x4 s3 = *(const f32x4*)(srow + 12);
        *(f32x4*)(orow + 0)  = s0 + xv0;
        *(f32x4*)(orow + 4)  = s1 + xv1;
        *(f32x4*)(orow + 8)  = s2 + xv2;
        *(f32x4*)(orow + 12) = s3 + xv3;
    }
}

extern "C" void kernel_launch(void* const* d_in, const int* in_sizes, int n_in,
                              void* d_out, int out_size, void* d_ws, size_t ws_size,
                              hipStream_t stream) {
    const float* x  = (const float*)d_in[0];
    const float* w1 = (const float*)d_in[1];
    const float* b1 = (const float*)d_in[2];
    const float* w3 = (const float*)d_in[3];
    const float* b3 = (const float*)d_in[4];
    const float* w5 = (const float*)d_in[5];
    const float* b5 = (const float*)d_in[6];
    const float* wc = (const float*)d_in[7];
    const float* bc = (const float*)d_in[8];
    float* out = (float*)d_out;
    uint16_t* aT = (uint16_t*)d_ws;    // 32*4100*256*2 B = 67.2 MB

    prep_kernel<<<dim3(CH), dim3(CH), 0, stream>>>(w1, b1, w3, b3, w5, b5, wc, bc);
    gelu_tr_kernel<<<dim3(TLEN / 64, CH / 64, BATCH), dim3(256), 0, stream>>>(x, aT);
    gemm_kernel<<<dim3(TLEN / TN, BATCH), dim3(256), 0, stream>>>(aT, x, out);
}

// Round 21
// 120.735 us; speedup vs baseline: 1.3237x; 1.0346x over previous
//
#include <hip/hip_runtime.h>
#include <stdint.h>

#define BATCH 32
#define CH    256
#define TLEN  4096
#define TN    64
#define SLS   72            // sL row stride (u16), k1-proven swizzle domain
#define SST   68            // phase-B f32 scratch row stride

typedef short    bf16x8 __attribute__((ext_vector_type(8)));
typedef float    f32x4  __attribute__((ext_vector_type(4)));
typedef uint16_t u16x4  __attribute__((ext_vector_type(4)));
typedef uint16_t u16x8  __attribute__((ext_vector_type(8)));

// packed fragment-order weights: g_wpk[(s*CH + co)*32 + g*8 + e] = w1eff[co][32s+8g+e]
__device__ __attribute__((aligned(16))) uint16_t g_wpk[CH * CH];
__device__ __attribute__((aligned(16))) float g_tap[5 * CH];   // tap-major
__device__ __attribute__((aligned(16))) float g_bias[CH];

static __device__ __forceinline__ uint16_t f32_to_bf16(float f) {
    uint32_t u = __builtin_bit_cast(uint32_t, f);
    u += 0x7FFFu + ((u >> 16) & 1u);
    return (uint16_t)(u >> 16);
}
static __device__ __forceinline__ float bf16_to_f32(uint16_t h) {
    uint32_t u = ((uint32_t)h) << 16;
    return __builtin_bit_cast(float, u);
}
// tanh-form gelu folded into exp2
static __device__ __forceinline__ float gelu_fast(float x) {
    const float A = 2.3022082f;
    const float B = 0.10294331f;
    float x2 = x * x;
    float z  = x * fmaf(x2, B, A);
    float e  = exp2f(z);
    float r  = __builtin_amdgcn_rcpf(1.0f + e);
    return fmaf(-x, r, x);
}

__global__ void prep_kernel(const float* __restrict__ w1, const float* __restrict__ b1,
                            const float* __restrict__ w3, const float* __restrict__ b3,
                            const float* __restrict__ w5, const float* __restrict__ b5,
                            const float* __restrict__ wc, const float* __restrict__ bc) {
    const int o = blockIdx.x;
    const int c = threadIdx.x;
    const float wc0 = wc[o * 3 + 0];
    const int s = c >> 5, g = (c >> 3) & 3, e = c & 7;
    g_wpk[(s * CH + o) * 32 + g * 8 + e] = f32_to_bf16(wc0 * w1[o * CH + c]);
    if (c == 0) {
        const float wc1 = wc[o * 3 + 1], wc2 = wc[o * 3 + 2];
        g_tap[0 * CH + o] = wc2 * w5[o * 5 + 0];
        g_tap[1 * CH + o] = wc1 * w3[o * 3 + 0] + wc2 * w5[o * 5 + 1];
        g_tap[2 * CH + o] = wc1 * w3[o * 3 + 1] + wc2 * w5[o * 5 + 2];
        g_tap[3 * CH + o] = wc1 * w3[o * 3 + 2] + wc2 * w5[o * 5 + 3];
        g_tap[4 * CH + o] = wc2 * w5[o * 5 + 4];
        g_bias[o] = wc0 * b1[o] + wc1 * b3[o] + wc2 * b5[o] + bc[o];
    }
}

// Fused kernel: per block = (batch b, 64-t tile), 4 waves.
// Stage 1 (per wave, channels c0=wid*64): load x (f32x4, gelu, pack), write
//   64 main rows into wave-private sL[64][72] (k1's bank-safe swizzle:
//   u16x8 block b8 at col (b8 ^ (ch>>3))<<3), tail rows 64..67 into sLtail.
// Stage 2 (per wave): LDS transpose sL -> sA[r68][c ^ ((r68+6)&7)<<3] (u16x8).
// Then (identical to r20's k2): K-loop w/ packed weights, phase A depthwise
// fold, phase B via sA-reuse scratch, residual from x (L3).
__global__ __launch_bounds__(256, 2)
void fused_kernel(const float* __restrict__ x, float* __restrict__ out) {
    __shared__ __attribute__((aligned(16))) uint16_t sL[4 * 64 * SLS];   // 36864 B
    __shared__ __attribute__((aligned(16))) uint16_t sLt[4 * 64 * 4];    //  2048 B
    __shared__ __attribute__((aligned(16))) uint16_t sA[68 * CH];        // 34816 B

    const int tid  = threadIdx.x;
    const int lane = tid & 63;
    const int wid  = tid >> 6;
    const int b    = blockIdx.y;
    const int t0   = blockIdx.x * TN;
    const int c0   = wid * 64;

    const float* __restrict__ xb = x + (size_t)b * CH * TLEN;
    float* __restrict__ ob = out + (size_t)b * CH * TLEN;

    uint16_t* __restrict__ sLw = sL  + wid * (64 * SLS);
    uint16_t* __restrict__ sTw = sLt + wid * (64 * 4);

    // ---- stage 1a: main 64 rows (t = t0-2 .. t0+61), lane = (cl 0..15, q 0..3) ----
    {
        const int cl = lane >> 2;
        const int q  = lane & 3;
#pragma unroll
        for (int rr = 0; rr < 4; ++rr) {
            const int ch = cl * 4 + rr;            // 0..63 local channel
            const float* xr = xb + (size_t)(c0 + ch) * TLEN + (t0 - 2 + q * 16);
            f32x4 v0, v1, v2, v3;
            if (blockIdx.x > 0) {
                v0 = *(const f32x4*)(xr + 0);
                v1 = *(const f32x4*)(xr + 4);
                v2 = *(const f32x4*)(xr + 8);
                v3 = *(const f32x4*)(xr + 12);
            } else {
                const int gbase = t0 - 2 + q * 16;
#pragma unroll
                for (int j = 0; j < 4; ++j) {
                    v0[j] = (gbase + j      >= 0) ? xr[j]      : 0.0f;
                    v1[j] = xr[4 + j];   // gbase+4 >= 2 always
                    v2[j] = xr[8 + j];
                    v3[j] = xr[12 + j];
                }
            }
            u16x8 p0, p1;
#pragma unroll
            for (int j = 0; j < 4; ++j) {
                p0[j]     = f32_to_bf16(gelu_fast(v0[j]));
                p0[4 + j] = f32_to_bf16(gelu_fast(v1[j]));
                p1[j]     = f32_to_bf16(gelu_fast(v2[j]));
                p1[4 + j] = f32_to_bf16(gelu_fast(v3[j]));
            }
            const int b0 = (((q * 2 + 0) ^ (ch >> 3)) << 3);
            const int b1 = (((q * 2 + 1) ^ (ch >> 3)) << 3);
            *(u16x8*)(&sLw[ch * SLS + b0]) = p0;
            *(u16x8*)(&sLw[ch * SLS + b1]) = p1;
        }
    }
    // ---- stage 1b: tail rows r68 = 64..67 (t = t0+62..t0+65), c = tid ----
    {
        const int ch = lane;                       // local channel within own wave
        const float* xr = xb + (size_t)(c0 + ch) * TLEN + (t0 + 62);
        if (blockIdx.x < gridDim.x - 1) {
#pragma unroll
            for (int k = 0; k < 4; ++k)
                sTw[ch * 4 + k] = f32_to_bf16(gelu_fast(xr[k]));
        } else {
#pragma unroll
            for (int k = 0; k < 4; ++k) {
                float v = (t0 + 62 + k < TLEN) ? xr[k] : 0.0f;
                sTw[ch * 4 + k] = f32_to_bf16(gelu_fast(v));
            }
        }
    }
    __builtin_amdgcn_s_waitcnt(0);   // wave-private sL/sLt writes complete (lgkmcnt 0)

    // ---- stage 2: per-wave transpose sL -> sA (544 u16x8 chunks per wave) ----
#pragma unroll
    for (int k = 0; k < 9; ++k) {
        const int idx = lane + k * 64;
        if (idx < 544) {
            const int r68 = idx >> 3;              // 0..67
            const int chb = idx & 7;               // 8-channel chunk
            u16x8 o;
            if (r68 < 64) {
                const int cin = (r68 & 7) | ((((r68 >> 3) ^ chb) & 7) << 3);
#pragma unroll
                for (int j = 0; j < 8; ++j) o[j] = sLw[(chb * 8 + j) * SLS + cin];
            } else {
#pragma unroll
                for (int j = 0; j < 8; ++j) o[j] = sTw[(chb * 8 + j) * 4 + (r68 & 3)];
            }
            const int swz = ((r68 + 6) & 7) << 3;
            *(u16x8*)(&sA[r68 * CH + ((c0 + chb * 8) ^ swz)]) = o;
        }
    }
    __syncthreads();   // B1: sA fully staged

    f32x4 acc[4][4];
    const f32x4 vzero = {0.f, 0.f, 0.f, 0.f};
#pragma unroll
    for (int mi = 0; mi < 4; ++mi)
#pragma unroll
        for (int ni = 0; ni < 4; ++ni) acc[mi][ni] = vzero;

    const int m0   = wid * 64;
    const int colt = lane & 15;
    const int kgrp = (lane >> 4) * 8;

    // ---- K loop, 1-deep ping-pong; packed weights (contiguous 1KB/wave-load) ----
    const int swzB = (colt & 7) << 3;
    int rowB[4];
#pragma unroll
    for (int ni = 0; ni < 4; ++ni) rowB[ni] = (ni * 16 + colt + 2) * CH;

    bf16x8 afb[2][4], bfb[2][4];
#pragma unroll
    for (int mi = 0; mi < 4; ++mi) {
        const int co = m0 + mi * 16 + colt;
        afb[0][mi] = *(const bf16x8*)(g_wpk + co * 32 + kgrp);
    }
#pragma unroll
    for (int ni = 0; ni < 4; ++ni)
        bfb[0][ni] = *(const bf16x8*)(&sA[rowB[ni] + (kgrp ^ swzB)]);
#pragma unroll
    for (int s = 0; s < 8; ++s) {
        const int cur = s & 1, nxt = cur ^ 1;
        if (s < 7) {
            const int sbase = (s + 1) * CH * 32;
#pragma unroll
            for (int mi = 0; mi < 4; ++mi) {
                const int co = m0 + mi * 16 + colt;
                afb[nxt][mi] = *(const bf16x8*)(g_wpk + sbase + co * 32 + kgrp);
            }
            const int cin = (s + 1) * 32 + kgrp;
#pragma unroll
            for (int ni = 0; ni < 4; ++ni)
                bfb[nxt][ni] = *(const bf16x8*)(&sA[rowB[ni] + (cin ^ swzB)]);
        }
#pragma unroll
        for (int mi = 0; mi < 4; ++mi)
#pragma unroll
            for (int ni = 0; ni < 4; ++ni)
                acc[mi][ni] = __builtin_amdgcn_mfma_f32_16x16x32_bf16(afb[cur][mi], bfb[cur][ni], acc[mi][ni], 0, 0, 0);
    }

    // ---- phase A: depthwise + bias folded into acc ----
    const int rg = (lane >> 4) * 4;
    int swzA[5];
#pragma unroll
    for (int k = 0; k < 5; ++k) swzA[k] = ((colt + k + 6) & 7) << 3;
#pragma unroll
    for (int mi = 0; mi < 4; ++mi) {
        const int c = m0 + mi * 16 + rg;
        const f32x4 tp0 = *(const f32x4*)(g_tap + 0 * CH + c);
        const f32x4 tp1 = *(const f32x4*)(g_tap + 1 * CH + c);
        const f32x4 tp2 = *(const f32x4*)(g_tap + 2 * CH + c);
        const f32x4 tp3 = *(const f32x4*)(g_tap + 3 * CH + c);
        const f32x4 tp4 = *(const f32x4*)(g_tap + 4 * CH + c);
        const f32x4 bsv = *(const f32x4*)(g_bias + c);
#pragma unroll
        for (int ni = 0; ni < 4; ++ni) {
            const int t = ni * 16 + colt;
            u16x4 a0 = *(const u16x4*)(&sA[(t + 0) * CH + (c ^ swzA[0])]);
            u16x4 a1 = *(const u16x4*)(&sA[(t + 1) * CH + (c ^ swzA[1])]);
            u16x4 a2 = *(const u16x4*)(&sA[(t + 2) * CH + (c ^ swzA[2])]);
            u16x4 a3 = *(const u16x4*)(&sA[(t + 3) * CH + (c ^ swzA[3])]);
            u16x4 a4 = *(const u16x4*)(&sA[(t + 4) * CH + (c ^ swzA[4])]);
#pragma unroll
            for (int r = 0; r < 4; ++r) {
                float d = tp0[r] * bf16_to_f32(a0[r]);
                d = fmaf(tp1[r], bf16_to_f32(a1[r]), d);
                d = fmaf(tp2[r], bf16_to_f32(a2[r]), d);
                d = fmaf(tp3[r], bf16_to_f32(a3[r]), d);
                d = fmaf(tp4[r], bf16_to_f32(a4[r]), d);
                acc[mi][ni][r] += d + bsv[r];
            }
        }
    }
    __syncthreads();   // B2: all sA reads done; sA storage becomes f32 scratch

    // ---- phase B: wave-private transpose through sA; exact f32 residual ----
    float* __restrict__ sw = ((float*)sA) + wid * (16 * SST);   // 4352 B per wave
    const int ci = lane >> 2;          // 0..15 channel-local
    const int q  = lane & 3;           // 0..3 -> 16 t each

#pragma unroll
    for (int mi = 0; mi < 4; ++mi) {
        const int cc = m0 + mi * 16 + ci;
        const float* xrow = xb + (size_t)cc * TLEN + t0 + q * 16;
        f32x4 xv0 = *(const f32x4*)(xrow + 0);
        f32x4 xv1 = *(const f32x4*)(xrow + 4);
        f32x4 xv2 = *(const f32x4*)(xrow + 8);
        f32x4 xv3 = *(const f32x4*)(xrow + 12);
#pragma unroll
        for (int ni = 0; ni < 4; ++ni) {
            const int t = ni * 16 + colt;
#pragma unroll
            for (int r = 0; r < 4; ++r) sw[(rg + r) * SST + t] = acc[mi][ni][r];
        }
        float* orow = ob + (size_t)cc * TLEN + t0 + q * 16;
        const float* srow = sw + ci * SST + q * 16;
        f32x4 s0 = *(const f32x4*)(srow + 0);
        f32x4 s1 = *(const f32x4*)(srow + 4);
        f32x4 s2 = *(const f32x4*)(srow + 8);
        f32x4 s3 = *(const f32x4*)(srow + 12);
        *(f32x4*)(orow + 0)  = s0 + xv0;
        *(f32x4*)(orow + 4)  = s1 + xv1;
        *(f32x4*)(orow + 8)  = s2 + xv2;
        *(f32x4*)(orow + 12) = s3 + xv3;
    }
}

extern "C" void kernel_launch(void* const* d_in, const int* in_sizes, int n_in,
                              void* d_out, int out_size, void* d_ws, size_t ws_size,
                              hipStream_t stream) {
    const float* x  = (const float*)d_in[0];
    const float* w1 = (const float*)d_in[1];
    const float* b1 = (const float*)d_in[2];
    const float* w3 = (const float*)d_in[3];
    const float* b3 = (const float*)d_in[4];
    const float* w5 = (const float*)d_in[5];
    const float* b5 = (const float*)d_in[6];
    const float* wc = (const float*)d_in[7];
    const float* bc = (const float*)d_in[8];
    float* out = (float*)d_out;

    prep_kernel<<<dim3(CH), dim3(CH), 0, stream>>>(w1, b1, w3, b3, w5, b5, wc, bc);
    fused_kernel<<<dim3(TLEN / TN, BATCH), dim3(256), 0, stream>>>(x, out);
}

// Round 22
// 118.030 us; speedup vs baseline: 1.3540x; 1.0229x over previous
//
#include <hip/hip_runtime.h>
#include <stdint.h>

#define BATCH 32
#define CH    256
#define TLEN  4096
#define TN    32
#define NRW   36            // sA rows staged: t0-2 .. t0+33
#define TPAD  4100          // aT rows per batch strip: 2 pad + 4096 + 2 pad
#define SST   36            // phase-B f32 scratch row stride

typedef short    bf16x8 __attribute__((ext_vector_type(8)));
typedef float    f32x4  __attribute__((ext_vector_type(4)));
typedef uint16_t u16x4  __attribute__((ext_vector_type(4)));
typedef uint16_t u16x8  __attribute__((ext_vector_type(8)));

// packed fragment-order weights: g_wpk[(s*CH + co)*32 + g*8 + e] = w1eff[co][32s+8g+e]
__device__ __attribute__((aligned(16))) uint16_t g_wpk[CH * CH];
__device__ __attribute__((aligned(16))) float g_tap[5 * CH];   // tap-major
__device__ __attribute__((aligned(16))) float g_bias[CH];

static __device__ __forceinline__ uint16_t f32_to_bf16(float f) {
    uint32_t u = __builtin_bit_cast(uint32_t, f);
    u += 0x7FFFu + ((u >> 16) & 1u);
    return (uint16_t)(u >> 16);
}
static __device__ __forceinline__ float bf16_to_f32(uint16_t h) {
    uint32_t u = ((uint32_t)h) << 16;
    return __builtin_bit_cast(float, u);
}
// tanh-form gelu folded into exp2
static __device__ __forceinline__ float gelu_fast(float x) {
    const float A = 2.3022082f;
    const float B = 0.10294331f;
    float x2 = x * x;
    float z  = x * fmaf(x2, B, A);
    float e  = exp2f(z);
    float r  = __builtin_amdgcn_rcpf(1.0f + e);
    return fmaf(-x, r, x);
}

__global__ void prep_kernel(const float* __restrict__ w1, const float* __restrict__ b1,
                            const float* __restrict__ w3, const float* __restrict__ b3,
                            const float* __restrict__ w5, const float* __restrict__ b5,
                            const float* __restrict__ wc, const float* __restrict__ bc) {
    const int o = blockIdx.x;
    const int c = threadIdx.x;
    const float wc0 = wc[o * 3 + 0];
    const int s = c >> 5, g = (c >> 3) & 3, e = c & 7;
    g_wpk[(s * CH + o) * 32 + g * 8 + e] = f32_to_bf16(wc0 * w1[o * CH + c]);
    if (c == 0) {
        const float wc1 = wc[o * 3 + 1], wc2 = wc[o * 3 + 2];
        g_tap[0 * CH + o] = wc2 * w5[o * 5 + 0];
        g_tap[1 * CH + o] = wc1 * w3[o * 3 + 0] + wc2 * w5[o * 5 + 1];
        g_tap[2 * CH + o] = wc1 * w3[o * 3 + 1] + wc2 * w5[o * 5 + 2];
        g_tap[3 * CH + o] = wc1 * w3[o * 3 + 2] + wc2 * w5[o * 5 + 3];
        g_tap[4 * CH + o] = wc2 * w5[o * 5 + 4];
        g_bias[o] = wc0 * b1[o] + wc1 * b3[o] + wc2 * b5[o] + bc[o];
    }
}

// k1: gelu + cast + transpose into aT[b][strip_row][c] bf16, where
// strip_row = 2 + t, element (t,c) stored at col c ^ ((t&7)<<3).
// sL swizzle: element (c=cr, t) lives at sL[cr*72 + ((t&7) | (((t>>3)^(cr>>3))<<3))]
__global__ __launch_bounds__(256, 4)
void gelu_tr_kernel(const float* __restrict__ x, uint16_t* __restrict__ aT) {
    __shared__ __attribute__((aligned(16))) uint16_t sL[64 * 72];   // 9216 B

    const int tid = threadIdx.x;
    const int tb = blockIdx.x, cb = blockIdx.y, b = blockIdx.z;
    const int t0 = tb * 64, c0 = cb * 64;

    {
        const int cr = tid >> 2;       // 0..63 channel-local
        const int q  = tid & 3;        // 0..3 t-quarter (16 t)
        const float* xr = x + ((size_t)(b * CH + c0 + cr)) * TLEN + t0 + q * 16;
        f32x4 v0 = *(const f32x4*)(xr + 0);
        f32x4 v1 = *(const f32x4*)(xr + 4);
        f32x4 v2 = *(const f32x4*)(xr + 8);
        f32x4 v3 = *(const f32x4*)(xr + 12);
        u16x8 p0, p1;
#pragma unroll
        for (int j = 0; j < 4; ++j) {
            p0[j]     = f32_to_bf16(gelu_fast(v0[j]));
            p0[4 + j] = f32_to_bf16(gelu_fast(v1[j]));
            p1[j]     = f32_to_bf16(gelu_fast(v2[j]));
            p1[4 + j] = f32_to_bf16(gelu_fast(v3[j]));
        }
        const int b0 = (((q * 2 + 0) ^ (cr >> 3)) << 3);
        const int b1 = (((q * 2 + 1) ^ (cr >> 3)) << 3);
        *(u16x8*)(&sL[cr * 72 + b0]) = p0;
        *(u16x8*)(&sL[cr * 72 + b1]) = p1;
    }
    __syncthreads();

    uint16_t* aTb = aT + (size_t)b * TPAD * CH;
#pragma unroll
    for (int i = 0; i < 2; ++i) {
        const int idx = tid + i * 256;
        const int tr  = idx >> 3;      // 0..63
        const int ch  = idx & 7;       // 0..7 c-chunk
        const int t   = t0 + tr;
        const int swz = (t & 7) << 3;
        const int cin = (tr & 7) | ((((tr >> 3) ^ ch) & 7) << 3);
        u16x8 o;
#pragma unroll
        for (int j = 0; j < 8; ++j) o[j] = sL[(ch * 8 + j) * 72 + cin];
        *(u16x8*)(&aTb[(size_t)(2 + t) * CH + ((c0 + ch * 8) ^ swz)]) = o;
    }
    if (tb == 0) {
        const int pr = tid >> 6;       // 0..3
        const int cc = c0 + (tid & 63);
        const int prow = (pr < 2) ? pr : (4098 + (pr - 2));
        const int tmod = (pr < 2) ? (6 + pr) : (pr - 2);   // (t&7) of the pad row
        aTb[(size_t)prow * CH + (cc ^ (tmod << 3))] = 0;
    }
}

// k2: TN=32 high-occupancy variant. Per (b, 32-t tile): linear 18.4 KB staging
// (loads issued before LDS writes), pipelined K-loop with packed coalesced
// weights, in-register depthwise fold, then sA storage reused as wave-private
// transpose scratch. LDS 18.4 KB -> 8 blocks/CU by LDS; target VGPR <= 64
// (launch_bounds(256,4)) -> up to 8 waves/SIMD co-resident.
// sA row r <-> global t = t0 + r - 2; swizzle of row r = ((r+6)&7)<<3.
__global__ __launch_bounds__(256, 4)
void gemm_kernel(const uint16_t* __restrict__ aT, const float* __restrict__ x,
                 float* __restrict__ out) {
    __shared__ __attribute__((aligned(16))) uint16_t sA[NRW * CH];     // 18432 B

    const int tid  = threadIdx.x;
    const int lane = tid & 63;
    const int wid  = tid >> 6;
    const int b    = blockIdx.y;
    const int t0   = blockIdx.x * TN;

    const float* __restrict__ xb = x + (size_t)b * CH * TLEN;
    float* __restrict__ ob = out + (size_t)b * CH * TLEN;

    // ---- staging: 1152 16B chunks; all loads issued before any LDS write ----
    {
        const u16x8* gsrc = (const u16x8*)(aT + (size_t)b * TPAD * CH + (size_t)t0 * CH);
        u16x8 stg[4], stgT;
#pragma unroll
        for (int i = 0; i < 4; ++i) stg[i] = gsrc[tid + i * 256];
        const bool tail = (tid < 128);
        if (tail) stgT = gsrc[tid + 1024];
        u16x8* ldst = (u16x8*)sA;
#pragma unroll
        for (int i = 0; i < 4; ++i) ldst[tid + i * 256] = stg[i];
        if (tail) ldst[tid + 1024] = stgT;
    }
    __syncthreads();   // B1

    f32x4 acc[4][2];
    const f32x4 vzero = {0.f, 0.f, 0.f, 0.f};
#pragma unroll
    for (int mi = 0; mi < 4; ++mi)
#pragma unroll
        for (int ni = 0; ni < 2; ++ni) acc[mi][ni] = vzero;

    const int m0   = wid * 64;
    const int colt = lane & 15;
    const int kgrp = (lane >> 4) * 8;

    // ---- K loop, 1-deep ping-pong; packed weights (contiguous 1KB/wave-load) ----
    const int swzB = (colt & 7) << 3;
    int rowB[2];
#pragma unroll
    for (int ni = 0; ni < 2; ++ni) rowB[ni] = (ni * 16 + colt + 2) * CH;

    bf16x8 afb[2][4], bfb[2][2];
#pragma unroll
    for (int mi = 0; mi < 4; ++mi) {
        const int co = m0 + mi * 16 + colt;
        afb[0][mi] = *(const bf16x8*)(g_wpk + co * 32 + kgrp);
    }
#pragma unroll
    for (int ni = 0; ni < 2; ++ni)
        bfb[0][ni] = *(const bf16x8*)(&sA[rowB[ni] + (kgrp ^ swzB)]);
#pragma unroll
    for (int s = 0; s < 8; ++s) {
        const int cur = s & 1, nxt = cur ^ 1;
        if (s < 7) {
            const int sbase = (s + 1) * CH * 32;
#pragma unroll
            for (int mi = 0; mi < 4; ++mi) {
                const int co = m0 + mi * 16 + colt;
                afb[nxt][mi] = *(const bf16x8*)(g_wpk + sbase + co * 32 + kgrp);
            }
            const int cin = (s + 1) * 32 + kgrp;
#pragma unroll
            for (int ni = 0; ni < 2; ++ni)
                bfb[nxt][ni] = *(const bf16x8*)(&sA[rowB[ni] + (cin ^ swzB)]);
        }
#pragma unroll
        for (int mi = 0; mi < 4; ++mi)
#pragma unroll
            for (int ni = 0; ni < 2; ++ni)
                acc[mi][ni] = __builtin_amdgcn_mfma_f32_16x16x32_bf16(afb[cur][mi], bfb[cur][ni], acc[mi][ni], 0, 0, 0);
    }

    // ---- phase A: depthwise + bias folded into acc ----
    const int rg = (lane >> 4) * 4;
    int swzA[5];
#pragma unroll
    for (int k = 0; k < 5; ++k) swzA[k] = ((colt + k + 6) & 7) << 3;
#pragma unroll
    for (int mi = 0; mi < 4; ++mi) {
        const int c = m0 + mi * 16 + rg;
        const f32x4 tp0 = *(const f32x4*)(g_tap + 0 * CH + c);
        const f32x4 tp1 = *(const f32x4*)(g_tap + 1 * CH + c);
        const f32x4 tp2 = *(const f32x4*)(g_tap + 2 * CH + c);
        const f32x4 tp3 = *(const f32x4*)(g_tap + 3 * CH + c);
        const f32x4 tp4 = *(const f32x4*)(g_tap + 4 * CH + c);
        const f32x4 bsv = *(const f32x4*)(g_bias + c);
#pragma unroll
        for (int ni = 0; ni < 2; ++ni) {
            const int t = ni * 16 + colt;
            u16x4 a0 = *(const u16x4*)(&sA[(t + 0) * CH + (c ^ swzA[0])]);
            u16x4 a1 = *(const u16x4*)(&sA[(t + 1) * CH + (c ^ swzA[1])]);
            u16x4 a2 = *(const u16x4*)(&sA[(t + 2) * CH + (c ^ swzA[2])]);
            u16x4 a3 = *(const u16x4*)(&sA[(t + 3) * CH + (c ^ swzA[3])]);
            u16x4 a4 = *(const u16x4*)(&sA[(t + 4) * CH + (c ^ swzA[4])]);
#pragma unroll
            for (int r = 0; r < 4; ++r) {
                float d = tp0[r] * bf16_to_f32(a0[r]);
                d = fmaf(tp1[r], bf16_to_f32(a1[r]), d);
                d = fmaf(tp2[r], bf16_to_f32(a2[r]), d);
                d = fmaf(tp3[r], bf16_to_f32(a3[r]), d);
                d = fmaf(tp4[r], bf16_to_f32(a4[r]), d);
                acc[mi][ni][r] += d + bsv[r];
            }
        }
    }
    __syncthreads();   // B2: all sA reads done; sA storage becomes f32 scratch

    // ---- phase B: wave-private transpose through sA; exact f32 residual ----
    float* __restrict__ sw = ((float*)sA) + wid * (16 * SST);   // 2304 B per wave
    const int ci = lane >> 2;          // 0..15 channel-local
    const int q  = lane & 3;           // 0..3 -> 8 t each

#pragma unroll
    for (int mi = 0; mi < 4; ++mi) {
        const int cc = m0 + mi * 16 + ci;
        const float* xrow = xb + (size_t)cc * TLEN + t0 + q * 8;
        f32x4 xv0 = *(const f32x4*)(xrow + 0);
        f32x4 xv1 = *(const f32x4*)(xrow + 4);
#pragma unroll
        for (int ni = 0; ni < 2; ++ni) {
            const int t = ni * 16 + colt;
#pragma unroll
            for (int r = 0; r < 4; ++r) sw[(rg + r) * SST + t] = acc[mi][ni][r];
        }
        float* orow = ob + (size_t)cc * TLEN + t0 + q * 8;
        const float* srow = sw + ci * SST + q * 8;
        f32x4 s0 = *(const f32x4*)(srow + 0);
        f32x4 s1 = *(const f32x4*)(srow + 4);
        *(f32x4*)(orow + 0) = s0 + xv0;
        *(f32x4*)(orow + 4) = s1 + xv1;
    }
}

extern "C" void kernel_launch(void* const* d_in, const int* in_sizes, int n_in,
                              void* d_out, int out_size, void* d_ws, size_t ws_size,
                              hipStream_t stream) {
    const float* x  = (const float*)d_in[0];
    const float* w1 = (const float*)d_in[1];
    const float* b1 = (const float*)d_in[2];
    const float* w3 = (const float*)d_in[3];
    const float* b3 = (const float*)d_in[4];
    const float* w5 = (const float*)d_in[5];
    const float* b5 = (const float*)d_in[6];
    const float* wc = (const float*)d_in[7];
    const float* bc = (const float*)d_in[8];
    float* out = (float*)d_out;
    uint16_t* aT = (uint16_t*)d_ws;    // 32*4100*256*2 B = 67.2 MB

    prep_kernel<<<dim3(CH), dim3(CH), 0, stream>>>(w1, b1, w3, b3, w5, b5, wc, bc);
    gelu_tr_kernel<<<dim3(TLEN / 64, CH / 64, BATCH), dim3(256), 0, stream>>>(x, aT);
    gemm_kernel<<<dim3(TLEN / TN, BATCH), dim3(256), 0, stream>>>(aT, x, out);
}

// Round 23
// 116.559 us; speedup vs baseline: 1.3711x; 1.0126x over previous
//
#include <hip/hip_runtime.h>
#include <stdint.h>

#define BATCH 32
#define CH    256
#define TLEN  4096
#define TN    32
#define NRW   36            // sA rows staged: t0-2 .. t0+33
#define TPAD  4100          // aT rows per batch strip: 2 pad + 4096 + 2 pad
#define SST   36            // phase-B f32 scratch row stride

typedef short    bf16x8 __attribute__((ext_vector_type(8)));
typedef float    f32x4  __attribute__((ext_vector_type(4)));
typedef uint16_t u16x4  __attribute__((ext_vector_type(4)));
typedef uint16_t u16x8  __attribute__((ext_vector_type(8)));

// packed fragment-order weights: g_wpk[(s*CH + co)*32 + g*8 + e] = w1eff[co][32s+8g+e]
__device__ __attribute__((aligned(16))) uint16_t g_wpk[CH * CH];
__device__ __attribute__((aligned(16))) float g_tap[5 * CH];   // tap-major
__device__ __attribute__((aligned(16))) float g_bias[CH];

static __device__ __forceinline__ uint16_t f32_to_bf16(float f) {
    uint32_t u = __builtin_bit_cast(uint32_t, f);
    u += 0x7FFFu + ((u >> 16) & 1u);
    return (uint16_t)(u >> 16);
}
static __device__ __forceinline__ float bf16_to_f32(uint16_t h) {
    uint32_t u = ((uint32_t)h) << 16;
    return __builtin_bit_cast(float, u);
}
// tanh-form gelu folded into exp2
static __device__ __forceinline__ float gelu_fast(float x) {
    const float A = 2.3022082f;
    const float B = 0.10294331f;
    float x2 = x * x;
    float z  = x * fmaf(x2, B, A);
    float e  = exp2f(z);
    float r  = __builtin_amdgcn_rcpf(1.0f + e);
    return fmaf(-x, r, x);
}

__global__ void prep_kernel(const float* __restrict__ w1, const float* __restrict__ b1,
                            const float* __restrict__ w3, const float* __restrict__ b3,
                            const float* __restrict__ w5, const float* __restrict__ b5,
                            const float* __restrict__ wc, const float* __restrict__ bc) {
    const int o = blockIdx.x;
    const int c = threadIdx.x;
    const float wc0 = wc[o * 3 + 0];
    const int s = c >> 5, g = (c >> 3) & 3, e = c & 7;
    g_wpk[(s * CH + o) * 32 + g * 8 + e] = f32_to_bf16(wc0 * w1[o * CH + c]);
    if (c == 0) {
        const float wc1 = wc[o * 3 + 1], wc2 = wc[o * 3 + 2];
        g_tap[0 * CH + o] = wc2 * w5[o * 5 + 0];
        g_tap[1 * CH + o] = wc1 * w3[o * 3 + 0] + wc2 * w5[o * 5 + 1];
        g_tap[2 * CH + o] = wc1 * w3[o * 3 + 1] + wc2 * w5[o * 5 + 2];
        g_tap[3 * CH + o] = wc1 * w3[o * 3 + 2] + wc2 * w5[o * 5 + 3];
        g_tap[4 * CH + o] = wc2 * w5[o * 5 + 4];
        g_bias[o] = wc0 * b1[o] + wc1 * b3[o] + wc2 * b5[o] + bc[o];
    }
}

// k1: gelu + cast + transpose into aT[b][strip_row][c] bf16, where
// strip_row = 2 + t, element (t,c) stored at col c ^ ((t&7)<<3).
// sL swizzle: element (c=cr, t) lives at sL[cr*72 + ((t&7) | (((t>>3)^(cr>>3))<<3))]
__global__ __launch_bounds__(256, 4)
void gelu_tr_kernel(const float* __restrict__ x, uint16_t* __restrict__ aT) {
    __shared__ __attribute__((aligned(16))) uint16_t sL[64 * 72];   // 9216 B

    const int tid = threadIdx.x;
    const int tb = blockIdx.x, cb = blockIdx.y, b = blockIdx.z;
    const int t0 = tb * 64, c0 = cb * 64;

    {
        const int cr = tid >> 2;       // 0..63 channel-local
        const int q  = tid & 3;        // 0..3 t-quarter (16 t)
        const float* xr = x + ((size_t)(b * CH + c0 + cr)) * TLEN + t0 + q * 16;
        f32x4 v0 = *(const f32x4*)(xr + 0);
        f32x4 v1 = *(const f32x4*)(xr + 4);
        f32x4 v2 = *(const f32x4*)(xr + 8);
        f32x4 v3 = *(const f32x4*)(xr + 12);
        u16x8 p0, p1;
#pragma unroll
        for (int j = 0; j < 4; ++j) {
            p0[j]     = f32_to_bf16(gelu_fast(v0[j]));
            p0[4 + j] = f32_to_bf16(gelu_fast(v1[j]));
            p1[j]     = f32_to_bf16(gelu_fast(v2[j]));
            p1[4 + j] = f32_to_bf16(gelu_fast(v3[j]));
        }
        const int b0 = (((q * 2 + 0) ^ (cr >> 3)) << 3);
        const int b1 = (((q * 2 + 1) ^ (cr >> 3)) << 3);
        *(u16x8*)(&sL[cr * 72 + b0]) = p0;
        *(u16x8*)(&sL[cr * 72 + b1]) = p1;
    }
    __syncthreads();

    uint16_t* aTb = aT + (size_t)b * TPAD * CH;
#pragma unroll
    for (int i = 0; i < 2; ++i) {
        const int idx = tid + i * 256;
        const int tr  = idx >> 3;      // 0..63
        const int ch  = idx & 7;       // 0..7 c-chunk
        const int t   = t0 + tr;
        const int swz = (t & 7) << 3;
        const int cin = (tr & 7) | ((((tr >> 3) ^ ch) & 7) << 3);
        u16x8 o;
#pragma unroll
        for (int j = 0; j < 8; ++j) o[j] = sL[(ch * 8 + j) * 72 + cin];
        *(u16x8*)(&aTb[(size_t)(2 + t) * CH + ((c0 + ch * 8) ^ swz)]) = o;
    }
    if (tb == 0) {
        const int pr = tid >> 6;       // 0..3
        const int cc = c0 + (tid & 63);
        const int prow = (pr < 2) ? pr : (4098 + (pr - 2));
        const int tmod = (pr < 2) ? (6 + pr) : (pr - 2);   // (t&7) of the pad row
        aTb[(size_t)prow * CH + (cc ^ (tmod << 3))] = 0;
    }
}

// k2: 512 threads = 8 waves, each owning M=32 channels of a (b, 32-t) tile.
// Weights live ENTIRELY in registers: wfr[8][2] = 64 VGPR/wave, loaded first
// (16 coalesced 1KB wave-loads) so their latency hides under the staging wait
// (vmcnt FIFO). K-loop is pure {ds_read ping-pong + MFMA} - no global loads.
// sA row r <-> global t = t0 + r - 2; swizzle of row r = ((r+6)&7)<<3.
__global__ __launch_bounds__(512, 2)
void gemm_kernel(const uint16_t* __restrict__ aT, const float* __restrict__ x,
                 float* __restrict__ out) {
    __shared__ __attribute__((aligned(16))) uint16_t sA[NRW * CH];     // 18432 B

    const int tid  = threadIdx.x;
    const int lane = tid & 63;
    const int wid  = tid >> 6;         // 0..7
    const int b    = blockIdx.y;
    const int t0   = blockIdx.x * TN;

    const float* __restrict__ xb = x + (size_t)b * CH * TLEN;
    float* __restrict__ ob = out + (size_t)b * CH * TLEN;

    const int m0   = wid * 32;         // wave's 32-channel group
    const int colt = lane & 15;
    const int kgrp = (lane >> 4) * 8;

    // ---- weight panel into registers FIRST (latency hides under staging) ----
    bf16x8 wfr[8][2];
#pragma unroll
    for (int s = 0; s < 8; ++s)
#pragma unroll
        for (int mi = 0; mi < 2; ++mi) {
            const int co = m0 + mi * 16 + colt;
            wfr[s][mi] = *(const bf16x8*)(g_wpk + (s * CH + co) * 32 + kgrp);
        }

    // ---- staging: 1152 16B chunks over 512 threads ----
    {
        const u16x8* gsrc = (const u16x8*)(aT + (size_t)b * TPAD * CH + (size_t)t0 * CH);
        u16x8 stg[2], stgT;
#pragma unroll
        for (int i = 0; i < 2; ++i) stg[i] = gsrc[tid + i * 512];
        const bool tail = (tid < 128);
        if (tail) stgT = gsrc[tid + 1024];
        u16x8* ldst = (u16x8*)sA;
#pragma unroll
        for (int i = 0; i < 2; ++i) ldst[tid + i * 512] = stg[i];
        if (tail) ldst[tid + 1024] = stgT;
    }
    __syncthreads();   // B1

    f32x4 acc[2][2];
    const f32x4 vzero = {0.f, 0.f, 0.f, 0.f};
#pragma unroll
    for (int mi = 0; mi < 2; ++mi)
#pragma unroll
        for (int ni = 0; ni < 2; ++ni) acc[mi][ni] = vzero;

    // ---- K loop: pure LDS ping-pong + MFMA (weights from VGPRs) ----
    const int swzB = (colt & 7) << 3;
    int rowB[2];
#pragma unroll
    for (int ni = 0; ni < 2; ++ni) rowB[ni] = (ni * 16 + colt + 2) * CH;

    bf16x8 bfb[2][2];
#pragma unroll
    for (int ni = 0; ni < 2; ++ni)
        bfb[0][ni] = *(const bf16x8*)(&sA[rowB[ni] + (kgrp ^ swzB)]);
#pragma unroll
    for (int s = 0; s < 8; ++s) {
        const int cur = s & 1, nxt = cur ^ 1;
        if (s < 7) {
            const int cin = (s + 1) * 32 + kgrp;
#pragma unroll
            for (int ni = 0; ni < 2; ++ni)
                bfb[nxt][ni] = *(const bf16x8*)(&sA[rowB[ni] + (cin ^ swzB)]);
        }
#pragma unroll
        for (int mi = 0; mi < 2; ++mi)
#pragma unroll
            for (int ni = 0; ni < 2; ++ni)
                acc[mi][ni] = __builtin_amdgcn_mfma_f32_16x16x32_bf16(wfr[s][mi], bfb[cur][ni], acc[mi][ni], 0, 0, 0);
    }

    // ---- phase A: depthwise + bias folded into acc ----
    const int rg = (lane >> 4) * 4;
    int swzA[5];
#pragma unroll
    for (int k = 0; k < 5; ++k) swzA[k] = ((colt + k + 6) & 7) << 3;
#pragma unroll
    for (int mi = 0; mi < 2; ++mi) {
        const int c = m0 + mi * 16 + rg;
        const f32x4 tp0 = *(const f32x4*)(g_tap + 0 * CH + c);
        const f32x4 tp1 = *(const f32x4*)(g_tap + 1 * CH + c);
        const f32x4 tp2 = *(const f32x4*)(g_tap + 2 * CH + c);
        const f32x4 tp3 = *(const f32x4*)(g_tap + 3 * CH + c);
        const f32x4 tp4 = *(const f32x4*)(g_tap + 4 * CH + c);
        const f32x4 bsv = *(const f32x4*)(g_bias + c);
#pragma unroll
        for (int ni = 0; ni < 2; ++ni) {
            const int t = ni * 16 + colt;
            u16x4 a0 = *(const u16x4*)(&sA[(t + 0) * CH + (c ^ swzA[0])]);
            u16x4 a1 = *(const u16x4*)(&sA[(t + 1) * CH + (c ^ swzA[1])]);
            u16x4 a2 = *(const u16x4*)(&sA[(t + 2) * CH + (c ^ swzA[2])]);
            u16x4 a3 = *(const u16x4*)(&sA[(t + 3) * CH + (c ^ swzA[3])]);
            u16x4 a4 = *(const u16x4*)(&sA[(t + 4) * CH + (c ^ swzA[4])]);
#pragma unroll
            for (int r = 0; r < 4; ++r) {
                float d = tp0[r] * bf16_to_f32(a0[r]);
                d = fmaf(tp1[r], bf16_to_f32(a1[r]), d);
                d = fmaf(tp2[r], bf16_to_f32(a2[r]), d);
                d = fmaf(tp3[r], bf16_to_f32(a3[r]), d);
                d = fmaf(tp4[r], bf16_to_f32(a4[r]), d);
                acc[mi][ni][r] += d + bsv[r];
            }
        }
    }
    __syncthreads();   // B2: all sA reads done; sA storage becomes f32 scratch

    // ---- phase B: wave-private transpose through sA; exact f32 residual ----
    float* __restrict__ sw = ((float*)sA) + wid * (16 * SST);   // 2304 B per wave
    const int ci = lane >> 2;          // 0..15 channel-local (within 16-ch group)
    const int q  = lane & 3;           // 0..3 -> 8 t each

#pragma unroll
    for (int mi = 0; mi < 2; ++mi) {
        const int cc = m0 + mi * 16 + ci;
        const float* xrow = xb + (size_t)cc * TLEN + t0 + q * 8;
        f32x4 xv0 = *(const f32x4*)(xrow + 0);
        f32x4 xv1 = *(const f32x4*)(xrow + 4);
#pragma unroll
        for (int ni = 0; ni < 2; ++ni) {
            const int t = ni * 16 + colt;
#pragma unroll
            for (int r = 0; r < 4; ++r) sw[(rg + r) * SST + t] = acc[mi][ni][r];
        }
        float* orow = ob + (size_t)cc * TLEN + t0 + q * 8;
        const float* srow = sw + ci * SST + q * 8;
        f32x4 s0 = *(const f32x4*)(srow + 0);
        f32x4 s1 = *(const f32x4*)(srow + 4);
        *(f32x4*)(orow + 0) = s0 + xv0;
        *(f32x4*)(orow + 4) = s1 + xv1;
    }
}

extern "C" void kernel_launch(void* const* d_in, const int* in_sizes, int n_in,
                              void* d_out, int out_size, void* d_ws, size_t ws_size,
                              hipStream_t stream) {
    const float* x  = (const float*)d_in[0];
    const float* w1 = (const float*)d_in[1];
    const float* b1 = (const float*)d_in[2];
    const float* w3 = (const float*)d_in[3];
    const float* b3 = (const float*)d_in[4];
    const float* w5 = (const float*)d_in[5];
    const float* b5 = (const float*)d_in[6];
    const float* wc = (const float*)d_in[7];
    const float* bc = (const float*)d_in[8];
    float* out = (float*)d_out;
    uint16_t* aT = (uint16_t*)d_ws;    // 32*4100*256*2 B = 67.2 MB

    prep_kernel<<<dim3(CH), dim3(CH), 0, stream>>>(w1, b1, w3, b3, w5, b5, wc, bc);
    gelu_tr_kernel<<<dim3(TLEN / 64, CH / 64, BATCH), dim3(256), 0, stream>>>(x, aT);
    gemm_kernel<<<dim3(TLEN / TN, BATCH), dim3(512), 0, stream>>>(aT, x, out);
}

// Round 24
// 104.455 us; speedup vs baseline: 1.5300x; 1.1159x over previous
//
#include <hip/hip_runtime.h>
#include <stdint.h>

#define BATCH 32
#define CH    256
#define TLEN  4096
#define TN    32
#define NT    8             // tiles per block (block covers 256 t)
#define NRW   36            // sA rows per tile: t0-2 .. t0+33
#define TPAD  4100          // aT rows per batch strip: 2 pad + 4096 + 2 pad
#define SST   36            // phase-B f32 scratch row stride

typedef short    bf16x8 __attribute__((ext_vector_type(8)));
typedef float    f32x4  __attribute__((ext_vector_type(4)));
typedef uint16_t u16x4  __attribute__((ext_vector_type(4)));
typedef uint16_t u16x8  __attribute__((ext_vector_type(8)));

// packed fragment-order weights: g_wpk[(s*CH + co)*32 + g*8 + e] = w1eff[co][32s+8g+e]
__device__ __attribute__((aligned(16))) uint16_t g_wpk[CH * CH];
__device__ __attribute__((aligned(16))) float g_tap[5 * CH];   // tap-major
__device__ __attribute__((aligned(16))) float g_bias[CH];

static __device__ __forceinline__ uint16_t f32_to_bf16(float f) {
    uint32_t u = __builtin_bit_cast(uint32_t, f);
    u += 0x7FFFu + ((u >> 16) & 1u);
    return (uint16_t)(u >> 16);
}
static __device__ __forceinline__ float bf16_to_f32(uint16_t h) {
    uint32_t u = ((uint32_t)h) << 16;
    return __builtin_bit_cast(float, u);
}
// tanh-form gelu folded into exp2
static __device__ __forceinline__ float gelu_fast(float x) {
    const float A = 2.3022082f;
    const float B = 0.10294331f;
    float x2 = x * x;
    float z  = x * fmaf(x2, B, A);
    float e  = exp2f(z);
    float r  = __builtin_amdgcn_rcpf(1.0f + e);
    return fmaf(-x, r, x);
}

__global__ void prep_kernel(const float* __restrict__ w1, const float* __restrict__ b1,
                            const float* __restrict__ w3, const float* __restrict__ b3,
                            const float* __restrict__ w5, const float* __restrict__ b5,
                            const float* __restrict__ wc, const float* __restrict__ bc) {
    const int o = blockIdx.x;
    const int c = threadIdx.x;
    const float wc0 = wc[o * 3 + 0];
    const int s = c >> 5, g = (c >> 3) & 3, e = c & 7;
    g_wpk[(s * CH + o) * 32 + g * 8 + e] = f32_to_bf16(wc0 * w1[o * CH + c]);
    if (c == 0) {
        const float wc1 = wc[o * 3 + 1], wc2 = wc[o * 3 + 2];
        g_tap[0 * CH + o] = wc2 * w5[o * 5 + 0];
        g_tap[1 * CH + o] = wc1 * w3[o * 3 + 0] + wc2 * w5[o * 5 + 1];
        g_tap[2 * CH + o] = wc1 * w3[o * 3 + 1] + wc2 * w5[o * 5 + 2];
        g_tap[3 * CH + o] = wc1 * w3[o * 3 + 2] + wc2 * w5[o * 5 + 3];
        g_tap[4 * CH + o] = wc2 * w5[o * 5 + 4];
        g_bias[o] = wc0 * b1[o] + wc1 * b3[o] + wc2 * b5[o] + bc[o];
    }
}

// k1: gelu + cast + transpose into aT[b][strip_row][c] bf16, where
// strip_row = 2 + t, element (t,c) stored at col c ^ ((t&7)<<3).
// sL swizzle: element (c=cr, t) lives at sL[cr*72 + ((t&7) | (((t>>3)^(cr>>3))<<3))]
__global__ __launch_bounds__(256, 4)
void gelu_tr_kernel(const float* __restrict__ x, uint16_t* __restrict__ aT) {
    __shared__ __attribute__((aligned(16))) uint16_t sL[64 * 72];   // 9216 B

    const int tid = threadIdx.x;
    const int tb = blockIdx.x, cb = blockIdx.y, b = blockIdx.z;
    const int t0 = tb * 64, c0 = cb * 64;

    {
        const int cr = tid >> 2;       // 0..63 channel-local
        const int q  = tid & 3;        // 0..3 t-quarter (16 t)
        const float* xr = x + ((size_t)(b * CH + c0 + cr)) * TLEN + t0 + q * 16;
        f32x4 v0 = *(const f32x4*)(xr + 0);
        f32x4 v1 = *(const f32x4*)(xr + 4);
        f32x4 v2 = *(const f32x4*)(xr + 8);
        f32x4 v3 = *(const f32x4*)(xr + 12);
        u16x8 p0, p1;
#pragma unroll
        for (int j = 0; j < 4; ++j) {
            p0[j]     = f32_to_bf16(gelu_fast(v0[j]));
            p0[4 + j] = f32_to_bf16(gelu_fast(v1[j]));
            p1[j]     = f32_to_bf16(gelu_fast(v2[j]));
            p1[4 + j] = f32_to_bf16(gelu_fast(v3[j]));
        }
        const int b0 = (((q * 2 + 0) ^ (cr >> 3)) << 3);
        const int b1 = (((q * 2 + 1) ^ (cr >> 3)) << 3);
        *(u16x8*)(&sL[cr * 72 + b0]) = p0;
        *(u16x8*)(&sL[cr * 72 + b1]) = p1;
    }
    __syncthreads();

    uint16_t* aTb = aT + (size_t)b * TPAD * CH;
#pragma unroll
    for (int i = 0; i < 2; ++i) {
        const int idx = tid + i * 256;
        const int tr  = idx >> 3;      // 0..63
        const int ch  = idx & 7;       // 0..7 c-chunk
        const int t   = t0 + tr;
        const int swz = (t & 7) << 3;
        const int cin = (tr & 7) | ((((tr >> 3) ^ ch) & 7) << 3);
        u16x8 o;
#pragma unroll
        for (int j = 0; j < 8; ++j) o[j] = sL[(ch * 8 + j) * 72 + cin];
        *(u16x8*)(&aTb[(size_t)(2 + t) * CH + ((c0 + ch * 8) ^ swz)]) = o;
    }
    if (tb == 0) {
        const int pr = tid >> 6;       // 0..3
        const int cc = c0 + (tid & 63);
        const int prow = (pr < 2) ? pr : (4098 + (pr - 2));
        const int tmod = (pr < 2) ? (6 + pr) : (pr - 2);   // (t&7) of the pad row
        aTb[(size_t)prow * CH + (cc ^ (tmod << 3))] = 0;
    }
}

// k2: persistent 8-tile march. 512 threads = 8 waves, each owning M=32 channels.
// Weights in AGPR/VGPR (wfr[8][2], loaded once per block). Double-buffered sA;
// per tile: issue reg-prefetch of tile i+1's aT chunks AND this tile's residual
// x rows -> K-loop (pure LDS+MFMA) -> phase A -> B2 -> phase B (scratch =
// retired buffer, residual from regs) -> write prefetch -> sA[nxt] -> B1.
// sA row r <-> t = t0 + r - 2; swizzle of row r = ((r+6)&7)<<3.
__global__ __launch_bounds__(512, 2)
void gemm_kernel(const uint16_t* __restrict__ aT, const float* __restrict__ x,
                 float* __restrict__ out) {
    __shared__ __attribute__((aligned(16))) uint16_t sA[2][NRW * CH];  // 36864 B

    const int tid  = threadIdx.x;
    const int lane = tid & 63;
    const int wid  = tid >> 6;         // 0..7
    const int b    = blockIdx.y;
    const int t0b  = blockIdx.x * (TN * NT);

    const float* __restrict__ xb = x + (size_t)b * CH * TLEN;
    float* __restrict__ ob = out + (size_t)b * CH * TLEN;
    const u16x8* __restrict__ gB = (const u16x8*)(aT + (size_t)b * TPAD * CH);
    // row r of tile t0 lives at chunk (t0 + r)*32 .. (CH/8 = 32 chunks/row)

    const int m0   = wid * 32;         // wave's 32-channel group
    const int colt = lane & 15;
    const int kgrp = (lane >> 4) * 8;
    const int rg   = (lane >> 4) * 4;
    const int ci   = lane >> 2;        // 0..15 channel-local (phase B)
    const int q4   = lane & 3;         // 0..3 -> 8 t each    (phase B)
    const bool tail = (tid < 128);

    // ---- weight panel into registers FIRST ----
    bf16x8 wfr[8][2];
#pragma unroll
    for (int s = 0; s < 8; ++s)
#pragma unroll
        for (int mi = 0; mi < 2; ++mi) {
            const int co = m0 + mi * 16 + colt;
            wfr[s][mi] = *(const bf16x8*)(g_wpk + (s * CH + co) * 32 + kgrp);
        }

    // ---- prologue: stage tile 0 into sA[0] ----
    {
        const u16x8* g0 = gB + (size_t)t0b * 32;
        u16x8 s0_ = g0[tid];
        u16x8 s1_ = g0[tid + 512];
        u16x8 sT_;
        if (tail) sT_ = g0[tid + 1024];
        u16x8* d = (u16x8*)sA[0];
        d[tid] = s0_; d[tid + 512] = s1_;
        if (tail) d[tid + 1024] = sT_;
    }
    __syncthreads();   // B1 (tile 0 ready)

    const int swzB = (colt & 7) << 3;
    int rowB[2];
#pragma unroll
    for (int ni = 0; ni < 2; ++ni) rowB[ni] = (ni * 16 + colt + 2) * CH;
    int swzA[5];
#pragma unroll
    for (int k = 0; k < 5; ++k) swzA[k] = ((colt + k + 6) & 7) << 3;

    for (int i = 0; i < NT; ++i) {
        const int cur = i & 1, nxt = cur ^ 1;
        const int t0 = t0b + i * TN;

        // ---- issue prefetches: tile i+1 staging chunks + tile i residual ----
        u16x8 p0, p1, pT;
        if (i + 1 < NT) {
            const u16x8* gn = gB + (size_t)(t0 + TN) * 32;
            p0 = gn[tid];
            p1 = gn[tid + 512];
            if (tail) pT = gn[tid + 1024];
        }
        f32x4 xv[2][2];
#pragma unroll
        for (int mi = 0; mi < 2; ++mi) {
            const int cc = m0 + mi * 16 + ci;
            const float* xr = xb + (size_t)cc * TLEN + t0 + q4 * 8;
            xv[mi][0] = *(const f32x4*)(xr + 0);
            xv[mi][1] = *(const f32x4*)(xr + 4);
        }

        const uint16_t* __restrict__ sAc = sA[cur];

        f32x4 acc[2][2];
        const f32x4 vzero = {0.f, 0.f, 0.f, 0.f};
#pragma unroll
        for (int mi = 0; mi < 2; ++mi)
#pragma unroll
            for (int ni = 0; ni < 2; ++ni) acc[mi][ni] = vzero;

        // ---- K loop: pure LDS ping-pong + MFMA (weights from regs) ----
        bf16x8 bfb[2][2];
#pragma unroll
        for (int ni = 0; ni < 2; ++ni)
            bfb[0][ni] = *(const bf16x8*)(&sAc[rowB[ni] + (kgrp ^ swzB)]);
#pragma unroll
        for (int s = 0; s < 8; ++s) {
            const int c2 = s & 1, nx = c2 ^ 1;
            if (s < 7) {
                const int cin = (s + 1) * 32 + kgrp;
#pragma unroll
                for (int ni = 0; ni < 2; ++ni)
                    bfb[nx][ni] = *(const bf16x8*)(&sAc[rowB[ni] + (cin ^ swzB)]);
            }
#pragma unroll
            for (int mi = 0; mi < 2; ++mi)
#pragma unroll
                for (int ni = 0; ni < 2; ++ni)
                    acc[mi][ni] = __builtin_amdgcn_mfma_f32_16x16x32_bf16(wfr[s][mi], bfb[c2][ni], acc[mi][ni], 0, 0, 0);
        }

        // ---- phase A: depthwise + bias folded into acc ----
#pragma unroll
        for (int mi = 0; mi < 2; ++mi) {
            const int c = m0 + mi * 16 + rg;
            const f32x4 tp0 = *(const f32x4*)(g_tap + 0 * CH + c);
            const f32x4 tp1 = *(const f32x4*)(g_tap + 1 * CH + c);
            const f32x4 tp2 = *(const f32x4*)(g_tap + 2 * CH + c);
            const f32x4 tp3 = *(const f32x4*)(g_tap + 3 * CH + c);
            const f32x4 tp4 = *(const f32x4*)(g_tap + 4 * CH + c);
            const f32x4 bsv = *(const f32x4*)(g_bias + c);
#pragma unroll
            for (int ni = 0; ni < 2; ++ni) {
                const int t = ni * 16 + colt;
                u16x4 a0 = *(const u16x4*)(&sAc[(t + 0) * CH + (c ^ swzA[0])]);
                u16x4 a1 = *(const u16x4*)(&sAc[(t + 1) * CH + (c ^ swzA[1])]);
                u16x4 a2 = *(const u16x4*)(&sAc[(t + 2) * CH + (c ^ swzA[2])]);
                u16x4 a3 = *(const u16x4*)(&sAc[(t + 3) * CH + (c ^ swzA[3])]);
                u16x4 a4 = *(const u16x4*)(&sAc[(t + 4) * CH + (c ^ swzA[4])]);
#pragma unroll
                for (int r = 0; r < 4; ++r) {
                    float d = tp0[r] * bf16_to_f32(a0[r]);
                    d = fmaf(tp1[r], bf16_to_f32(a1[r]), d);
                    d = fmaf(tp2[r], bf16_to_f32(a2[r]), d);
                    d = fmaf(tp3[r], bf16_to_f32(a3[r]), d);
                    d = fmaf(tp4[r], bf16_to_f32(a4[r]), d);
                    acc[mi][ni][r] += d + bsv[r];
                }
            }
        }
        __syncthreads();   // B2: all reads of sA[cur] done -> becomes f32 scratch

        // ---- phase B: wave-private transpose in retired buffer; residual from regs ----
        float* __restrict__ sw = ((float*)sA[cur]) + wid * (16 * SST);  // 2304 B/wave
#pragma unroll
        for (int mi = 0; mi < 2; ++mi) {
#pragma unroll
            for (int ni = 0; ni < 2; ++ni) {
                const int t = ni * 16 + colt;
#pragma unroll
                for (int r = 0; r < 4; ++r) sw[(rg + r) * SST + t] = acc[mi][ni][r];
            }
            const int cc = m0 + mi * 16 + ci;
            float* orow = ob + (size_t)cc * TLEN + t0 + q4 * 8;
            const float* srow = sw + ci * SST + q4 * 8;
            f32x4 s0 = *(const f32x4*)(srow + 0);
            f32x4 s1 = *(const f32x4*)(srow + 4);
            *(f32x4*)(orow + 0) = s0 + xv[mi][0];
            *(f32x4*)(orow + 4) = s1 + xv[mi][1];
        }

        // ---- commit prefetched tile i+1 into sA[nxt] ----
        if (i + 1 < NT) {
            u16x8* d = (u16x8*)sA[nxt];
            d[tid] = p0; d[tid + 512] = p1;
            if (tail) d[tid + 1024] = pT;
        }
        __syncthreads();   // B1: sA[nxt] ready; scratch use of sA[cur] complete
    }
}

extern "C" void kernel_launch(void* const* d_in, const int* in_sizes, int n_in,
                              void* d_out, int out_size, void* d_ws, size_t ws_size,
                              hipStream_t stream) {
    const float* x  = (const float*)d_in[0];
    const float* w1 = (const float*)d_in[1];
    const float* b1 = (const float*)d_in[2];
    const float* w3 = (const float*)d_in[3];
    const float* b3 = (const float*)d_in[4];
    const float* w5 = (const float*)d_in[5];
    const float* b5 = (const float*)d_in[6];
    const float* wc = (const float*)d_in[7];
    const float* bc = (const float*)d_in[8];
    float* out = (float*)d_out;
    uint16_t* aT = (uint16_t*)d_ws;    // 32*4100*256*2 B = 67.2 MB

    prep_kernel<<<dim3(CH), dim3(CH), 0, stream>>>(w1, b1, w3, b3, w5, b5, wc, bc);
    gelu_tr_kernel<<<dim3(TLEN / 64, CH / 64, BATCH), dim3(256), 0, stream>>>(x, aT);
    gemm_kernel<<<dim3(TLEN / (TN * NT), BATCH), dim3(512), 0, stream>>>(aT, x, out);
}